// Round 10
// baseline (4354.076 us; speedup 1.0000x reference)
//
#include <hip/hip_runtime.h>
#include <hip/hip_fp16.h>

#define N0C 200000
#define N1C 600000
#define N2C 400000
#define NRC (N0C + N1C + N2C)
#define NGC 128
#define D 32
#define SCAN_TILE 2048
#define CHUNK_EDGES 16384
#define NBUK_MAX 1184
#define LDSE 12288   // max edges per bucket for LDS sort (96 KB)

// act buffer row bases (rank-concatenated)
#define AB0 0
#define AB1 N0C
#define AB2 (N0C + N1C)

typedef __attribute__((ext_vector_type(8))) _Float16 half8;
typedef __attribute__((ext_vector_type(4))) float f32x4;

// ---------- scan helpers (for (bucket,chunk) histogram table) ----------
__global__ void scan_phase1(const int* __restrict__ counts, int* __restrict__ bsums, int n) {
    __shared__ int sd[256];
    int base = blockIdx.x * SCAN_TILE;
    int s = 0;
    for (int i = threadIdx.x; i < SCAN_TILE; i += 256) {
        int idx = base + i;
        s += (idx < n) ? counts[idx] : 0;
    }
    sd[threadIdx.x] = s;
    __syncthreads();
    for (int o = 128; o > 0; o >>= 1) {
        if (threadIdx.x < o) sd[threadIdx.x] += sd[threadIdx.x + o];
        __syncthreads();
    }
    if (threadIdx.x == 0) bsums[blockIdx.x] = sd[0];
}

__global__ void scan_phase2(int* __restrict__ bsums, int nb) {
    __shared__ int sd[1024];
    for (int i = threadIdx.x; i < nb; i += 256) sd[i] = bsums[i];
    __syncthreads();
    if (threadIdx.x == 0) {
        int acc = 0;
        for (int i = 0; i < nb; ++i) { int v = sd[i]; sd[i] = acc; acc += v; }
        bsums[nb] = acc;
    }
    __syncthreads();
    for (int i = threadIdx.x; i < nb; i += 256) bsums[i] = sd[i];
}

__global__ void scan_phase3(const int* __restrict__ counts, const int* __restrict__ bsums,
                            int* __restrict__ outscan, int n) {
    __shared__ int sd[256];
    int base = blockIdx.x * SCAN_TILE + threadIdx.x * 8;
    int v[8];
    int s = 0;
#pragma unroll
    for (int u = 0; u < 8; ++u) {
        int idx = base + u;
        int c = (idx < n) ? counts[idx] : 0;
        v[u] = s;
        s += c;
    }
    sd[threadIdx.x] = s;
    __syncthreads();
    if (threadIdx.x == 0) {
        int acc = bsums[blockIdx.x];
        for (int i = 0; i < 256; ++i) { int q = sd[i]; sd[i] = acc; acc += q; }
    }
    __syncthreads();
    int off = sd[threadIdx.x];
#pragma unroll
    for (int u = 0; u < 8; ++u) {
        int idx = base + u;
        if (idx < n) outscan[idx] = off + v[u];
    }
}

__global__ void set_final_kernel(int* __restrict__ dst, int v) { *dst = v; }

// ---------- binned build phase 1: per-chunk bucket histogram (transposed) ----------
__global__ __launch_bounds__(256) void bhist_kernel(const int* __restrict__ rows, int nnz,
                                                    int shift, int nbuk, int ncht, int chunk0,
                                                    int* __restrict__ HT) {
    __shared__ int h[NBUK_MAX];
    for (int i = threadIdx.x; i < nbuk; i += 256) h[i] = 0;
    __syncthreads();
    int base = blockIdx.x * CHUNK_EDGES;
    for (int i = threadIdx.x; i < CHUNK_EDGES; i += 256) {
        int e = base + i;
        if (e < nnz) atomicAdd(&h[rows[e] >> shift], 1);
    }
    __syncthreads();
    int c = chunk0 + blockIdx.x;
    for (int b = threadIdx.x; b < nbuk; b += 256) HT[b * ncht + c] = h[b];
}

// ---------- binned build phase 2: append into exclusive (bucket,chunk) stage ranges ----------
__global__ __launch_bounds__(256) void bin_kernel(const int* __restrict__ rows,
                                                  const int* __restrict__ cols,
                                                  const float* __restrict__ vals, int nnz,
                                                  int shift, int nbuk, int ncht, int chunk0,
                                                  int colbase, const int* __restrict__ HS,
                                                  int2* __restrict__ stage) {
    __shared__ int cur[NBUK_MAX];
    int c = chunk0 + blockIdx.x;
    for (int b = threadIdx.x; b < nbuk; b += 256) cur[b] = HS[b * ncht + c];
    __syncthreads();
    int base = blockIdx.x * CHUNK_EDGES;
    for (int i = threadIdx.x; i < CHUNK_EDGES; i += 256) {
        int e = base + i;
        if (e < nnz) {
            int r = rows[e];
            int b = r >> shift;
            int pos = atomicAdd(&cur[b], 1);
            int rl = r - (b << shift);
            stage[pos] = make_int2((rl << 22) | (cols[e] + colbase), __float_as_int(vals[e]));
        }
    }
}

__global__ void extract_b_kernel(const int* __restrict__ HS, int ncht, int nbuk, int total,
                                 int* __restrict__ B) {
    int b = blockIdx.x * blockDim.x + threadIdx.x;
    if (b < nbuk) B[b] = HS[b * ncht];
    if (b == nbuk) B[b] = total;
}

// ---------- binned build phase 3: per-bucket LDS counting sort -> GLOBAL rowptr + sequential cv ----------
__global__ __launch_bounds__(256) void binsort_kernel(const int2* __restrict__ stage,
                                                      const int* __restrict__ B, int shift,
                                                      int* __restrict__ rowptr,
                                                      int2* __restrict__ cv, int nrows,
                                                      int rowbase, int cvbase) {
    __shared__ int hcnt[512], sa[512], sb[512], rcur[512];
    __shared__ int2 buf[LDSE];
    int b = blockIdx.x;
    int s0 = B[b], s1 = B[b + 1];
    int cnt = s1 - s0;
    int nr = 1 << shift;
    int rb = b << shift;
    for (int i = threadIdx.x; i < nr; i += 256) hcnt[i] = 0;
    __syncthreads();
    for (int i = s0 + threadIdx.x; i < s1; i += 256)
        atomicAdd(&hcnt[(unsigned)stage[i].x >> 22], 1);
    __syncthreads();
    for (int i = threadIdx.x; i < nr; i += 256) sa[i] = hcnt[i];
    __syncthreads();
    int* curp = sa; int* nxtp = sb;
    for (int off = 1; off < nr; off <<= 1) {
        for (int i = threadIdx.x; i < nr; i += 256)
            nxtp[i] = (i >= off) ? curp[i - off] + curp[i] : curp[i];
        __syncthreads();
        int* t = curp; curp = nxtp; nxtp = t;
    }
    for (int i = threadIdx.x; i < nr; i += 256) {
        int excl = curp[i] - hcnt[i];
        rcur[i] = excl;
        int row = rb + i;
        if (row < nrows) rowptr[rowbase + row] = cvbase + s0 + excl;
    }
    __syncthreads();
    if (cnt <= LDSE) {
        for (int i = s0 + threadIdx.x; i < s1; i += 256) {
            int2 e = stage[i];
            int rl = (unsigned)e.x >> 22;
            int pos = atomicAdd(&rcur[rl], 1);
            buf[pos] = make_int2(e.x & 0x3FFFFF, e.y);
        }
        __syncthreads();
        for (int i = threadIdx.x; i < cnt; i += 256)
            cv[s0 + i] = buf[i];
    } else {
        for (int i = s0 + threadIdx.x; i < s1; i += 256) {
            int2 e = stage[i];
            int rl = (unsigned)e.x >> 22;
            int pos = atomicAdd(&rcur[rl], 1);
            cv[s0 + pos] = make_int2(e.x & 0x3FFFFF, e.y);
        }
    }
}

// ---------- fused MFMA projection: for NM mats sharing one source ----------
template <int DIN, int NM, bool F32>
__global__ __launch_bounds__(256) void xw_fused_kernel(
    const void* __restrict__ xsrc,
    const float* __restrict__ Wa, const float* __restrict__ Wb, const float* __restrict__ Wc,
    __half* __restrict__ oa, __half* __restrict__ ob, __half* __restrict__ oc, int n) {
    int wave = (blockIdx.x * 256 + threadIdx.x) >> 6;
    int lane = threadIdx.x & 63;
    int nwaves = (gridDim.x * 256) >> 6;
    int li = lane & 15;
    int lk = lane >> 4;
    const float* Ws[3] = { Wa, Wb, Wc };
    __half* Os[3] = { oa, ob, oc };
    half8 bfrag[NM][2][DIN / 32];
#pragma unroll
    for (int m = 0; m < NM; ++m)
#pragma unroll
        for (int ct = 0; ct < 2; ++ct)
#pragma unroll
            for (int ks = 0; ks < DIN / 32; ++ks)
#pragma unroll
                for (int r = 0; r < 8; ++r) {
                    int k = ks * 32 + lk * 8 + r;
                    int j = ct * 16 + li;
                    bfrag[m][ct][ks][r] = (_Float16)Ws[m][k * 32 + j];
                }
    int ntiles = (n + 15) >> 4;
    for (int t = wave; t < ntiles; t += nwaves) {
        int rbase = t << 4;
        int arow = rbase + li;
        int arowc = (arow < n) ? arow : (n - 1);
        half8 afrag[DIN / 32];
#pragma unroll
        for (int ks = 0; ks < DIN / 32; ++ks) {
            if (F32) {
                const float* p = (const float*)xsrc + (size_t)arowc * DIN + ks * 32 + lk * 8;
                float4 u = *(const float4*)p;
                float4 v = *(const float4*)(p + 4);
                afrag[ks] = (half8){ (_Float16)u.x, (_Float16)u.y, (_Float16)u.z, (_Float16)u.w,
                                     (_Float16)v.x, (_Float16)v.y, (_Float16)v.z, (_Float16)v.w };
            } else {
                afrag[ks] = *(const half8*)((const __half*)xsrc + (size_t)arowc * DIN +
                                            ks * 32 + lk * 8);
            }
        }
#pragma unroll
        for (int m = 0; m < NM; ++m) {
#pragma unroll
            for (int ct = 0; ct < 2; ++ct) {
                f32x4 acc = { 0.f, 0.f, 0.f, 0.f };
#pragma unroll
                for (int ks = 0; ks < DIN / 32; ++ks)
                    acc = __builtin_amdgcn_mfma_f32_16x16x32_f16(afrag[ks], bfrag[m][ct][ks],
                                                                 acc, 0, 0, 0);
#pragma unroll
                for (int r = 0; r < 4; ++r) {
                    int row = rbase + lk * 4 + r;
                    if (row < n)
                        Os[m][(size_t)row * 32 + ct * 16 + li] = __float2half(acc[r]);
                }
            }
        }
    }
}

// ---------- unified gather over global row space: 4 lanes/row, uint4 per lane ----------
__global__ __launch_bounds__(256, 8) void gather_kernel(
    const int* __restrict__ rp, const int2* __restrict__ cv,
    const __half* __restrict__ XW, __half* __restrict__ act,
    int row0, int nrange) {
    int g = (blockIdx.x * 256 + threadIdx.x) >> 2;
    int j = threadIdx.x & 3;
    if (g >= nrange) return;
    int row = row0 + g;
    int ks = rp[row], ke = rp[row + 1];
    float s[8] = { 0.f, 0.f, 0.f, 0.f, 0.f, 0.f, 0.f, 0.f };
    for (int k = ks; k < ke; k += 8) {
        int2 e[8];
#pragma unroll
        for (int u = 0; u < 8; ++u) {
            int kk = k + u;
            e[u] = cv[(kk < ke) ? kk : (ke - 1)];
        }
        uint4 q[8];
#pragma unroll
        for (int u = 0; u < 8; ++u)
            q[u] = *(const uint4*)(XW + (size_t)e[u].x * 32 + j * 8);
#pragma unroll
        for (int u = 0; u < 8; ++u) {
            float v = (k + u < ke) ? __int_as_float(e[u].y) : 0.f;
            const unsigned* qq = &q[u].x;
#pragma unroll
            for (int h = 0; h < 4; ++h) {
                __half2 h2 = *(__half2*)&qq[h];
                float2 f2 = __half22float2(h2);
                s[2 * h] = fmaf(v, f2.x, s[2 * h]);
                s[2 * h + 1] = fmaf(v, f2.y, s[2 * h + 1]);
            }
        }
    }
    float scale = (row < AB1) ? 0.5f : ((row < AB2) ? (1.f / 3.f) : 0.5f);
    uint4 ov;
    unsigned* op = &ov.x;
#pragma unroll
    for (int h = 0; h < 4; ++h) {
        __half2 o2 = __floats2half2_rn(fmaxf(s[2 * h], 0.f) * scale,
                                       fmaxf(s[2 * h + 1], 0.f) * scale);
        op[h] = *(unsigned*)&o2;
    }
    *(uint4*)(act + (size_t)row * 32 + j * 8) = ov;
}

// ---------- pooling: per-graph binary search + block reduction ----------
#define BPG 4
__global__ __launch_bounds__(256) void pool_kernel(const __half* __restrict__ x1,
                                                   const int* __restrict__ batch,
                                                   float* __restrict__ sums,
                                                   float* __restrict__ cnt, int n) {
    __shared__ float red[256][8];
    int g = blockIdx.x / BPG;
    int p = blockIdx.x % BPG;
    int lo = 0, hi = n;
    while (lo < hi) { int mid = (lo + hi) >> 1; if (batch[mid] < g) lo = mid + 1; else hi = mid; }
    int s0 = lo;
    lo = s0; hi = n;
    while (lo < hi) { int mid = (lo + hi) >> 1; if (batch[mid] < g + 1) lo = mid + 1; else hi = mid; }
    int s1 = lo;
    int tid = threadIdx.x;
    int qr = tid & 3;
    int rt = tid >> 2;
    float acc[8] = { 0.f, 0.f, 0.f, 0.f, 0.f, 0.f, 0.f, 0.f };
    for (int r = s0 + p * 64 + rt; r < s1; r += BPG * 64) {
        half8 v = *(const half8*)(x1 + (size_t)r * 32 + qr * 8);
#pragma unroll
        for (int u = 0; u < 8; ++u) acc[u] += fabsf((float)v[u]);
    }
#pragma unroll
    for (int u = 0; u < 8; ++u) red[tid][u] = acc[u];
    __syncthreads();
    for (int off = 128; off >= 4; off >>= 1) {
        if (tid < off) {
#pragma unroll
            for (int u = 0; u < 8; ++u) red[tid][u] += red[tid + off][u];
        }
        __syncthreads();
    }
    if (tid < 4) {
#pragma unroll
        for (int u = 0; u < 8; ++u)
            atomicAdd(&sums[(size_t)g * D + tid * 8 + u], red[tid][u]);
    }
    if (p == 0 && tid == 0) cnt[g] = (float)(s1 - s0);
}

// ---------- head ----------
__global__ void head_kernel(const float* __restrict__ sums, const float* __restrict__ cnt,
                            const float* __restrict__ w1, const float* __restrict__ b1,
                            const float* __restrict__ w2, const float* __restrict__ b2,
                            float* __restrict__ out) {
    __shared__ float W1s[D * D], W2s[D * 10], B1s[D], B2s[10];
    int tid = threadIdx.x;
    for (int i = tid; i < D * D; i += blockDim.x) W1s[i] = w1[i];
    for (int i = tid; i < D * 10; i += blockDim.x) W2s[i] = w2[i];
    if (tid < D) B1s[tid] = b1[tid];
    if (tid < 10) B2s[tid] = b2[tid];
    __syncthreads();
    int g = tid;
    if (g >= NGC) return;
    float invc = 1.f / fmaxf(cnt[g], 1.f);
    float p[D];
#pragma unroll
    for (int k = 0; k < D; ++k) p[k] = sums[(size_t)g * D + k] * invc;
    float h[D];
#pragma unroll
    for (int j = 0; j < D; ++j) {
        float s = B1s[j];
#pragma unroll
        for (int k = 0; k < D; ++k) s = fmaf(p[k], W1s[k * D + j], s);
        h[j] = fmaxf(s, 0.f);
    }
    float l[10];
    float m = -1e30f;
#pragma unroll
    for (int o = 0; o < 10; ++o) {
        float s = B2s[o];
#pragma unroll
        for (int k = 0; k < D; ++k) s = fmaf(h[k], W2s[k * 10 + o], s);
        l[o] = s;
        m = fmaxf(m, s);
    }
    float den = 0.f;
#pragma unroll
    for (int o = 0; o < 10; ++o) { l[o] = expf(l[o] - m); den += l[o]; }
    float inv = 1.f / den;
#pragma unroll
    for (int o = 0; o < 10; ++o) out[g * 10 + o] = l[o] * inv;
}

extern "C" void kernel_launch(void* const* d_in, const int* in_sizes, int n_in,
                              void* d_out, int out_size, void* d_ws, size_t ws_size,
                              hipStream_t stream) {
    const float* X0 = (const float*)d_in[0];
    const float* X1 = (const float*)d_in[1];
    const float* X2 = (const float*)d_in[2];
    // mats: 0=L0,1=L1,2=L2,3=B2D3,4=D2B1TD1inv,5=D1invB1,6=B2TD2inv
    const int* spr[7]; const int* spc[7]; const float* spv[7]; int spn[7];
    for (int m = 0; m < 7; ++m) {
        spr[m] = (const int*)d_in[3 + m * 3];
        spc[m] = (const int*)d_in[4 + m * 3];
        spv[m] = (const float*)d_in[5 + m * 3];
        spn[m] = in_sizes[3 + m * 3];
    }
    const int* batch1 = (const int*)d_in[24];
    const float* W1 = (const float*)d_in[25];
    const float* W234 = (const float*)d_in[26];
    const float* mlp1_w = (const float*)d_in[27];
    const float* mlp1_b = (const float*)d_in[28];
    const float* mlp2_w = (const float*)d_in[29];
    const float* mlp2_b = (const float*)d_in[30];
    float* out = (float*)d_out;

    const int srcrows_mat[7] = { N0C, N1C, N2C, N2C, N0C, N1C, N1C };
    int XB[7];
    {
        int acc = 0;
        for (int m = 0; m < 7; ++m) { XB[m] = acc; acc += srcrows_mat[m]; }
    }
    const int XWROWS = 3000000;

    struct RankDef { int nrows; int nmats; int mats[3]; int shift; int rowbase; };
    const RankDef rdefs[3] = {
        { N0C, 2, { 0, 5, -1 }, 8, AB0 },
        { N1C, 3, { 4, 1, 3 }, 9, AB1 },
        { N2C, 2, { 6, 2, -1 }, 9, AB2 },
    };

    // ---- workspace carve ----
    char* wp = (char*)d_ws;
    __half* act = (__half*)wp;             wp += (size_t)NRC * 32 * sizeof(__half);
    __half* XWbuf = (__half*)wp;           wp += (size_t)XWROWS * 32 * sizeof(__half);
    size_t total_nnz = 0;
    for (int m = 0; m < 7; ++m) total_nnz += (size_t)spn[m];
    int2* cv_base = (int2*)wp;             wp += total_nnz * sizeof(int2);
    int* rowptr = (int*)wp;                wp += (size_t)(NRC + 3) * sizeof(int);
    int* HT = (int*)wp;                    wp += (size_t)1000000 * sizeof(int);
    int* HS = (int*)wp;                    wp += (size_t)1000000 * sizeof(int);
    int* Bb = (int*)wp;                    wp += (size_t)(NBUK_MAX + 1) * sizeof(int);
    int* bsums = (int*)wp;                 wp += 1040 * sizeof(int);
    float* sums = (float*)wp;              wp += (size_t)NGC * D * sizeof(float);
    float* cnt = (float*)wp;               wp += (size_t)NGC * sizeof(float);

    int2* stage = (int2*)XWbuf;

    // ---- build unified CSR (3 rank sections) via binned sort ----
    {
        size_t cvoff = 0;
        for (int r = 0; r < 3; ++r) {
            const RankDef& rd = rdefs[r];
            int nr = rd.nrows;
            int shift = rd.shift;
            int nbuk = (nr + (1 << shift) - 1) >> shift;
            int2* cv_r = cv_base + cvoff;
            int rank_nnz = 0;
            int ncht = 0;
            int chunk0_mat[3] = { 0, 0, 0 };
            for (int i = 0; i < rd.nmats; ++i) {
                chunk0_mat[i] = ncht;
                ncht += (spn[rd.mats[i]] + CHUNK_EDGES - 1) / CHUNK_EDGES;
                rank_nnz += spn[rd.mats[i]];
            }

            for (int i = 0; i < rd.nmats; ++i) {
                int m = rd.mats[i];
                int gch = (spn[m] + CHUNK_EDGES - 1) / CHUNK_EDGES;
                bhist_kernel<<<gch, 256, 0, stream>>>(spr[m], spn[m], shift, nbuk, ncht,
                                                      chunk0_mat[i], HT);
            }
            int nht = nbuk * ncht;
            int nbh = (nht + SCAN_TILE - 1) / SCAN_TILE;
            scan_phase1<<<nbh, 256, 0, stream>>>(HT, bsums, nht);
            scan_phase2<<<1, 256, 0, stream>>>(bsums, nbh);
            scan_phase3<<<nbh, 256, 0, stream>>>(HT, bsums, HS, nht);
            extract_b_kernel<<<(nbuk + 256) / 256, 256, 0, stream>>>(HS, ncht, nbuk,
                                                                     rank_nnz, Bb);

            for (int i = 0; i < rd.nmats; ++i) {
                int m = rd.mats[i];
                int gch = (spn[m] + CHUNK_EDGES - 1) / CHUNK_EDGES;
                bin_kernel<<<gch, 256, 0, stream>>>(spr[m], spc[m], spv[m], spn[m], shift,
                                                    nbuk, ncht, chunk0_mat[i], XB[m], HS, stage);
            }
            binsort_kernel<<<nbuk, 256, 0, stream>>>(stage, Bb, shift, rowptr, cv_r, nr,
                                                     rd.rowbase, (int)cvoff);
            cvoff += (size_t)rank_nnz;
        }
        set_final_kernel<<<1, 1, 0, stream>>>(rowptr + NRC, (int)total_nnz);
    }

    // ---- 4 layers; layer 3 computes only what feeds the pooled x1 ----
    for (int l = 0; l < 4; ++l) {
        const float* Wl = (l == 0) ? W1 : W234 + (size_t)(l - 1) * 7 * 32 * 32;
        const size_t wst = (l == 0) ? (size_t)64 * 32 : (size_t)32 * 32;
#define WPK(k) (Wl + (size_t)(k) * wst)
#define SLOT(m) (XWbuf + (size_t)XB[m] * 32)
        if (l == 0) {
            xw_fused_kernel<64, 2, true><<<2048, 256, 0, stream>>>(
                X0, WPK(0), WPK(1), nullptr, SLOT(0), SLOT(4), nullptr, N0C);
            xw_fused_kernel<64, 3, true><<<2048, 256, 0, stream>>>(
                X1, WPK(2), WPK(3), WPK(4), SLOT(1), SLOT(5), SLOT(6), N1C);
            xw_fused_kernel<64, 2, true><<<2048, 256, 0, stream>>>(
                X2, WPK(6), WPK(5), nullptr, SLOT(2), SLOT(3), nullptr, N2C);
        } else if (l < 3) {
            xw_fused_kernel<32, 2, false><<<2048, 256, 0, stream>>>(
                act + (size_t)AB0 * 32, WPK(0), WPK(1), nullptr, SLOT(0), SLOT(4), nullptr, N0C);
            xw_fused_kernel<32, 3, false><<<2048, 256, 0, stream>>>(
                act + (size_t)AB1 * 32, WPK(2), WPK(3), WPK(4), SLOT(1), SLOT(5), SLOT(6), N1C);
            xw_fused_kernel<32, 2, false><<<2048, 256, 0, stream>>>(
                act + (size_t)AB2 * 32, WPK(6), WPK(5), nullptr, SLOT(2), SLOT(3), nullptr, N2C);
        } else {
            xw_fused_kernel<32, 1, false><<<2048, 256, 0, stream>>>(
                act + (size_t)AB0 * 32, WPK(1), nullptr, nullptr, SLOT(4), nullptr, nullptr, N0C);
            xw_fused_kernel<32, 1, false><<<2048, 256, 0, stream>>>(
                act + (size_t)AB1 * 32, WPK(2), nullptr, nullptr, SLOT(1), nullptr, nullptr, N1C);
            xw_fused_kernel<32, 1, false><<<2048, 256, 0, stream>>>(
                act + (size_t)AB2 * 32, WPK(5), nullptr, nullptr, SLOT(3), nullptr, nullptr, N2C);
        }
#undef WPK
#undef SLOT
        if (l < 3) {
            gather_kernel<<<(int)(((size_t)NRC * 4 + 255) / 256), 256, 0, stream>>>(
                rowptr, cv_base, XWbuf, act, 0, NRC);
        } else {
            gather_kernel<<<(int)(((size_t)N1C * 4 + 255) / 256), 256, 0, stream>>>(
                rowptr, cv_base, XWbuf, act, AB1, N1C);
        }
    }

    hipMemsetAsync(sums, 0, (size_t)(NGC * D + NGC) * sizeof(float), stream);
    pool_kernel<<<NGC * BPG, 256, 0, stream>>>(act + (size_t)AB1 * 32, batch1, sums, cnt, N1C);
    head_kernel<<<1, 128, 0, stream>>>(sums, cnt, mlp1_w, mlp1_b, mlp2_w, mlp2_b, out);
}

// Round 11
// 2554.870 us; speedup vs baseline: 1.7042x; 1.7042x over previous
//
#include <hip/hip_runtime.h>
#include <hip/hip_fp16.h>

#define N0C 200000
#define N1C 600000
#define N2C 400000
#define NRC (N0C + N1C + N2C)
#define NGC 128
#define D 32
#define SCAN_TILE 2048
#define CHUNK_EDGES 16384
#define NBUK_MAX 1184
#define LDSE 12288   // max edges per bucket for LDS sort (96 KB)

// act buffer row bases (rank-concatenated)
#define AB0 0
#define AB1 N0C
#define AB2 (N0C + N1C)

typedef __attribute__((ext_vector_type(8))) _Float16 half8;
typedef __attribute__((ext_vector_type(4))) float f32x4;

// ---------- scan helpers (for (bucket,chunk) histogram table) ----------
__global__ void scan_phase1(const int* __restrict__ counts, int* __restrict__ bsums, int n) {
    __shared__ int sd[256];
    int base = blockIdx.x * SCAN_TILE;
    int s = 0;
    for (int i = threadIdx.x; i < SCAN_TILE; i += 256) {
        int idx = base + i;
        s += (idx < n) ? counts[idx] : 0;
    }
    sd[threadIdx.x] = s;
    __syncthreads();
    for (int o = 128; o > 0; o >>= 1) {
        if (threadIdx.x < o) sd[threadIdx.x] += sd[threadIdx.x + o];
        __syncthreads();
    }
    if (threadIdx.x == 0) bsums[blockIdx.x] = sd[0];
}

__global__ void scan_phase2(int* __restrict__ bsums, int nb) {
    __shared__ int sd[1024];
    for (int i = threadIdx.x; i < nb; i += 256) sd[i] = bsums[i];
    __syncthreads();
    if (threadIdx.x == 0) {
        int acc = 0;
        for (int i = 0; i < nb; ++i) { int v = sd[i]; sd[i] = acc; acc += v; }
        bsums[nb] = acc;
    }
    __syncthreads();
    for (int i = threadIdx.x; i < nb; i += 256) bsums[i] = sd[i];
}

__global__ void scan_phase3(const int* __restrict__ counts, const int* __restrict__ bsums,
                            int* __restrict__ outscan, int n) {
    __shared__ int sd[256];
    int base = blockIdx.x * SCAN_TILE + threadIdx.x * 8;
    int v[8];
    int s = 0;
#pragma unroll
    for (int u = 0; u < 8; ++u) {
        int idx = base + u;
        int c = (idx < n) ? counts[idx] : 0;
        v[u] = s;
        s += c;
    }
    sd[threadIdx.x] = s;
    __syncthreads();
    if (threadIdx.x == 0) {
        int acc = bsums[blockIdx.x];
        for (int i = 0; i < 256; ++i) { int q = sd[i]; sd[i] = acc; acc += q; }
    }
    __syncthreads();
    int off = sd[threadIdx.x];
#pragma unroll
    for (int u = 0; u < 8; ++u) {
        int idx = base + u;
        if (idx < n) outscan[idx] = off + v[u];
    }
}

__global__ void set_final_kernel(int* __restrict__ dst, int v) { *dst = v; }

// ---------- binned build phase 1: per-chunk bucket histogram (transposed) ----------
__global__ __launch_bounds__(256) void bhist_kernel(const int* __restrict__ rows, int nnz,
                                                    int shift, int nbuk, int ncht, int chunk0,
                                                    int* __restrict__ HT) {
    __shared__ int h[NBUK_MAX];
    for (int i = threadIdx.x; i < nbuk; i += 256) h[i] = 0;
    __syncthreads();
    int base = blockIdx.x * CHUNK_EDGES;
    for (int i = threadIdx.x; i < CHUNK_EDGES; i += 256) {
        int e = base + i;
        if (e < nnz) atomicAdd(&h[rows[e] >> shift], 1);
    }
    __syncthreads();
    int c = chunk0 + blockIdx.x;
    for (int b = threadIdx.x; b < nbuk; b += 256) HT[b * ncht + c] = h[b];
}

// ---------- binned build phase 2: append into exclusive (bucket,chunk) stage ranges ----------
__global__ __launch_bounds__(256) void bin_kernel(const int* __restrict__ rows,
                                                  const int* __restrict__ cols,
                                                  const float* __restrict__ vals, int nnz,
                                                  int shift, int nbuk, int ncht, int chunk0,
                                                  int colbase, const int* __restrict__ HS,
                                                  int2* __restrict__ stage) {
    __shared__ int cur[NBUK_MAX];
    int c = chunk0 + blockIdx.x;
    for (int b = threadIdx.x; b < nbuk; b += 256) cur[b] = HS[b * ncht + c];
    __syncthreads();
    int base = blockIdx.x * CHUNK_EDGES;
    for (int i = threadIdx.x; i < CHUNK_EDGES; i += 256) {
        int e = base + i;
        if (e < nnz) {
            int r = rows[e];
            int b = r >> shift;
            int pos = atomicAdd(&cur[b], 1);
            int rl = r - (b << shift);
            stage[pos] = make_int2((rl << 22) | (cols[e] + colbase), __float_as_int(vals[e]));
        }
    }
}

__global__ void extract_b_kernel(const int* __restrict__ HS, int ncht, int nbuk, int total,
                                 int* __restrict__ B) {
    int b = blockIdx.x * blockDim.x + threadIdx.x;
    if (b < nbuk) B[b] = HS[b * ncht];
    if (b == nbuk) B[b] = total;
}

// ---------- binned build phase 3: per-bucket LDS counting sort -> GLOBAL rowptr + sequential cv ----------
__global__ __launch_bounds__(256) void binsort_kernel(const int2* __restrict__ stage,
                                                      const int* __restrict__ B, int shift,
                                                      int* __restrict__ rowptr,
                                                      int2* __restrict__ cv, int nrows,
                                                      int rowbase, int cvbase) {
    __shared__ int hcnt[512], sa[512], sb[512], rcur[512];
    __shared__ int2 buf[LDSE];
    int b = blockIdx.x;
    int s0 = B[b], s1 = B[b + 1];
    int cnt = s1 - s0;
    int nr = 1 << shift;
    int rb = b << shift;
    for (int i = threadIdx.x; i < nr; i += 256) hcnt[i] = 0;
    __syncthreads();
    for (int i = s0 + threadIdx.x; i < s1; i += 256)
        atomicAdd(&hcnt[(unsigned)stage[i].x >> 22], 1);
    __syncthreads();
    for (int i = threadIdx.x; i < nr; i += 256) sa[i] = hcnt[i];
    __syncthreads();
    int* curp = sa; int* nxtp = sb;
    for (int off = 1; off < nr; off <<= 1) {
        for (int i = threadIdx.x; i < nr; i += 256)
            nxtp[i] = (i >= off) ? curp[i - off] + curp[i] : curp[i];
        __syncthreads();
        int* t = curp; curp = nxtp; nxtp = t;
    }
    for (int i = threadIdx.x; i < nr; i += 256) {
        int excl = curp[i] - hcnt[i];
        rcur[i] = excl;
        int row = rb + i;
        if (row < nrows) rowptr[rowbase + row] = cvbase + s0 + excl;
    }
    __syncthreads();
    if (cnt <= LDSE) {
        for (int i = s0 + threadIdx.x; i < s1; i += 256) {
            int2 e = stage[i];
            int rl = (unsigned)e.x >> 22;
            int pos = atomicAdd(&rcur[rl], 1);
            buf[pos] = make_int2(e.x & 0x3FFFFF, e.y);
        }
        __syncthreads();
        for (int i = threadIdx.x; i < cnt; i += 256)
            cv[s0 + i] = buf[i];
    } else {
        for (int i = s0 + threadIdx.x; i < s1; i += 256) {
            int2 e = stage[i];
            int rl = (unsigned)e.x >> 22;
            int pos = atomicAdd(&rcur[rl], 1);
            cv[s0 + pos] = make_int2(e.x & 0x3FFFFF, e.y);
        }
    }
}

// ---------- fused MFMA projection: for NM mats sharing one source ----------
template <int DIN, int NM, bool F32>
__global__ __launch_bounds__(256) void xw_fused_kernel(
    const void* __restrict__ xsrc,
    const float* __restrict__ Wa, const float* __restrict__ Wb, const float* __restrict__ Wc,
    __half* __restrict__ oa, __half* __restrict__ ob, __half* __restrict__ oc, int n) {
    int wave = (blockIdx.x * 256 + threadIdx.x) >> 6;
    int lane = threadIdx.x & 63;
    int nwaves = (gridDim.x * 256) >> 6;
    int li = lane & 15;
    int lk = lane >> 4;
    const float* Ws[3] = { Wa, Wb, Wc };
    __half* Os[3] = { oa, ob, oc };
    half8 bfrag[NM][2][DIN / 32];
#pragma unroll
    for (int m = 0; m < NM; ++m)
#pragma unroll
        for (int ct = 0; ct < 2; ++ct)
#pragma unroll
            for (int ks = 0; ks < DIN / 32; ++ks)
#pragma unroll
                for (int r = 0; r < 8; ++r) {
                    int k = ks * 32 + lk * 8 + r;
                    int j = ct * 16 + li;
                    bfrag[m][ct][ks][r] = (_Float16)Ws[m][k * 32 + j];
                }
    int ntiles = (n + 15) >> 4;
    for (int t = wave; t < ntiles; t += nwaves) {
        int rbase = t << 4;
        int arow = rbase + li;
        int arowc = (arow < n) ? arow : (n - 1);
        half8 afrag[DIN / 32];
#pragma unroll
        for (int ks = 0; ks < DIN / 32; ++ks) {
            if (F32) {
                const float* p = (const float*)xsrc + (size_t)arowc * DIN + ks * 32 + lk * 8;
                float4 u = *(const float4*)p;
                float4 v = *(const float4*)(p + 4);
                afrag[ks] = (half8){ (_Float16)u.x, (_Float16)u.y, (_Float16)u.z, (_Float16)u.w,
                                     (_Float16)v.x, (_Float16)v.y, (_Float16)v.z, (_Float16)v.w };
            } else {
                afrag[ks] = *(const half8*)((const __half*)xsrc + (size_t)arowc * DIN +
                                            ks * 32 + lk * 8);
            }
        }
#pragma unroll
        for (int m = 0; m < NM; ++m) {
#pragma unroll
            for (int ct = 0; ct < 2; ++ct) {
                f32x4 acc = { 0.f, 0.f, 0.f, 0.f };
#pragma unroll
                for (int ks = 0; ks < DIN / 32; ++ks)
                    acc = __builtin_amdgcn_mfma_f32_16x16x32_f16(afrag[ks], bfrag[m][ct][ks],
                                                                 acc, 0, 0, 0);
#pragma unroll
                for (int r = 0; r < 4; ++r) {
                    int row = rbase + lk * 4 + r;
                    if (row < n)
                        Os[m][(size_t)row * 32 + ct * 16 + li] = __float2half(acc[r]);
                }
            }
        }
    }
}

// ---------- per-rank gather on global rowptr/cv: 4 lanes/row, uint4 per lane ----------
// NOTE: no min-waves clause — VGPR ~48 (needs q[8]=32 regs); forcing 8 waves/SIMD
// caps VGPR at 32 and spills to scratch (+2 GB traffic, 2.6x slower — round 10).
__global__ __launch_bounds__(256) void gather_kernel(
    const int* __restrict__ rp, const int2* __restrict__ cv,
    const __half* __restrict__ XW, __half* __restrict__ act,
    int row0, float scale, int nrange) {
    int g = (blockIdx.x * 256 + threadIdx.x) >> 2;
    int j = threadIdx.x & 3;
    if (g >= nrange) return;
    int row = row0 + g;
    int ks = rp[row], ke = rp[row + 1];
    float s[8] = { 0.f, 0.f, 0.f, 0.f, 0.f, 0.f, 0.f, 0.f };
    for (int k = ks; k < ke; k += 8) {
        int2 e[8];
#pragma unroll
        for (int u = 0; u < 8; ++u) {
            int kk = k + u;
            e[u] = cv[(kk < ke) ? kk : (ke - 1)];
        }
        uint4 q[8];
#pragma unroll
        for (int u = 0; u < 8; ++u)
            q[u] = *(const uint4*)(XW + (size_t)e[u].x * 32 + j * 8);
#pragma unroll
        for (int u = 0; u < 8; ++u) {
            float v = (k + u < ke) ? __int_as_float(e[u].y) : 0.f;
            const unsigned* qq = &q[u].x;
#pragma unroll
            for (int h = 0; h < 4; ++h) {
                __half2 h2 = *(__half2*)&qq[h];
                float2 f2 = __half22float2(h2);
                s[2 * h] = fmaf(v, f2.x, s[2 * h]);
                s[2 * h + 1] = fmaf(v, f2.y, s[2 * h + 1]);
            }
        }
    }
    uint4 ov;
    unsigned* op = &ov.x;
#pragma unroll
    for (int h = 0; h < 4; ++h) {
        __half2 o2 = __floats2half2_rn(fmaxf(s[2 * h], 0.f) * scale,
                                       fmaxf(s[2 * h + 1], 0.f) * scale);
        op[h] = *(unsigned*)&o2;
    }
    *(uint4*)(act + (size_t)row * 32 + j * 8) = ov;
}

// ---------- pooling: per-graph binary search + block reduction ----------
#define BPG 4
__global__ __launch_bounds__(256) void pool_kernel(const __half* __restrict__ x1,
                                                   const int* __restrict__ batch,
                                                   float* __restrict__ sums,
                                                   float* __restrict__ cnt, int n) {
    __shared__ float red[256][8];
    int g = blockIdx.x / BPG;
    int p = blockIdx.x % BPG;
    int lo = 0, hi = n;
    while (lo < hi) { int mid = (lo + hi) >> 1; if (batch[mid] < g) lo = mid + 1; else hi = mid; }
    int s0 = lo;
    lo = s0; hi = n;
    while (lo < hi) { int mid = (lo + hi) >> 1; if (batch[mid] < g + 1) lo = mid + 1; else hi = mid; }
    int s1 = lo;
    int tid = threadIdx.x;
    int qr = tid & 3;
    int rt = tid >> 2;
    float acc[8] = { 0.f, 0.f, 0.f, 0.f, 0.f, 0.f, 0.f, 0.f };
    for (int r = s0 + p * 64 + rt; r < s1; r += BPG * 64) {
        half8 v = *(const half8*)(x1 + (size_t)r * 32 + qr * 8);
#pragma unroll
        for (int u = 0; u < 8; ++u) acc[u] += fabsf((float)v[u]);
    }
#pragma unroll
    for (int u = 0; u < 8; ++u) red[tid][u] = acc[u];
    __syncthreads();
    for (int off = 128; off >= 4; off >>= 1) {
        if (tid < off) {
#pragma unroll
            for (int u = 0; u < 8; ++u) red[tid][u] += red[tid + off][u];
        }
        __syncthreads();
    }
    if (tid < 4) {
#pragma unroll
        for (int u = 0; u < 8; ++u)
            atomicAdd(&sums[(size_t)g * D + tid * 8 + u], red[tid][u]);
    }
    if (p == 0 && tid == 0) cnt[g] = (float)(s1 - s0);
}

// ---------- head ----------
__global__ void head_kernel(const float* __restrict__ sums, const float* __restrict__ cnt,
                            const float* __restrict__ w1, const float* __restrict__ b1,
                            const float* __restrict__ w2, const float* __restrict__ b2,
                            float* __restrict__ out) {
    __shared__ float W1s[D * D], W2s[D * 10], B1s[D], B2s[10];
    int tid = threadIdx.x;
    for (int i = tid; i < D * D; i += blockDim.x) W1s[i] = w1[i];
    for (int i = tid; i < D * 10; i += blockDim.x) W2s[i] = w2[i];
    if (tid < D) B1s[tid] = b1[tid];
    if (tid < 10) B2s[tid] = b2[tid];
    __syncthreads();
    int g = tid;
    if (g >= NGC) return;
    float invc = 1.f / fmaxf(cnt[g], 1.f);
    float p[D];
#pragma unroll
    for (int k = 0; k < D; ++k) p[k] = sums[(size_t)g * D + k] * invc;
    float h[D];
#pragma unroll
    for (int j = 0; j < D; ++j) {
        float s = B1s[j];
#pragma unroll
        for (int k = 0; k < D; ++k) s = fmaf(p[k], W1s[k * D + j], s);
        h[j] = fmaxf(s, 0.f);
    }
    float l[10];
    float m = -1e30f;
#pragma unroll
    for (int o = 0; o < 10; ++o) {
        float s = B2s[o];
#pragma unroll
        for (int k = 0; k < D; ++k) s = fmaf(h[k], W2s[k * 10 + o], s);
        l[o] = s;
        m = fmaxf(m, s);
    }
    float den = 0.f;
#pragma unroll
    for (int o = 0; o < 10; ++o) { l[o] = expf(l[o] - m); den += l[o]; }
    float inv = 1.f / den;
#pragma unroll
    for (int o = 0; o < 10; ++o) out[g * 10 + o] = l[o] * inv;
}

extern "C" void kernel_launch(void* const* d_in, const int* in_sizes, int n_in,
                              void* d_out, int out_size, void* d_ws, size_t ws_size,
                              hipStream_t stream) {
    const float* X0 = (const float*)d_in[0];
    const float* X1 = (const float*)d_in[1];
    const float* X2 = (const float*)d_in[2];
    // mats: 0=L0,1=L1,2=L2,3=B2D3,4=D2B1TD1inv,5=D1invB1,6=B2TD2inv
    const int* spr[7]; const int* spc[7]; const float* spv[7]; int spn[7];
    for (int m = 0; m < 7; ++m) {
        spr[m] = (const int*)d_in[3 + m * 3];
        spc[m] = (const int*)d_in[4 + m * 3];
        spv[m] = (const float*)d_in[5 + m * 3];
        spn[m] = in_sizes[3 + m * 3];
    }
    const int* batch1 = (const int*)d_in[24];
    const float* W1 = (const float*)d_in[25];
    const float* W234 = (const float*)d_in[26];
    const float* mlp1_w = (const float*)d_in[27];
    const float* mlp1_b = (const float*)d_in[28];
    const float* mlp2_w = (const float*)d_in[29];
    const float* mlp2_b = (const float*)d_in[30];
    float* out = (float*)d_out;

    const int srcrows_mat[7] = { N0C, N1C, N2C, N2C, N0C, N1C, N1C };
    int XB[7];
    {
        int acc = 0;
        for (int m = 0; m < 7; ++m) { XB[m] = acc; acc += srcrows_mat[m]; }
    }
    const int XWROWS = 3000000;

    struct RankDef { int nrows; int nmats; int mats[3]; int shift; int rowbase; };
    const RankDef rdefs[3] = {
        { N0C, 2, { 0, 5, -1 }, 8, AB0 },
        { N1C, 3, { 4, 1, 3 }, 9, AB1 },
        { N2C, 2, { 6, 2, -1 }, 9, AB2 },
    };

    // ---- workspace carve ----
    char* wp = (char*)d_ws;
    __half* act = (__half*)wp;             wp += (size_t)NRC * 32 * sizeof(__half);
    __half* XWbuf = (__half*)wp;           wp += (size_t)XWROWS * 32 * sizeof(__half);
    size_t total_nnz = 0;
    for (int m = 0; m < 7; ++m) total_nnz += (size_t)spn[m];
    int2* cv_base = (int2*)wp;             wp += total_nnz * sizeof(int2);
    int* rowptr = (int*)wp;                wp += (size_t)(NRC + 3) * sizeof(int);
    int* HT = (int*)wp;                    wp += (size_t)1000000 * sizeof(int);
    int* HS = (int*)wp;                    wp += (size_t)1000000 * sizeof(int);
    int* Bb = (int*)wp;                    wp += (size_t)(NBUK_MAX + 1) * sizeof(int);
    int* bsums = (int*)wp;                 wp += 1040 * sizeof(int);
    float* sums = (float*)wp;              wp += (size_t)NGC * D * sizeof(float);
    float* cnt = (float*)wp;               wp += (size_t)NGC * sizeof(float);

    int2* stage = (int2*)XWbuf;

    // ---- build unified CSR (3 rank sections) via binned sort ----
    {
        size_t cvoff = 0;
        for (int r = 0; r < 3; ++r) {
            const RankDef& rd = rdefs[r];
            int nr = rd.nrows;
            int shift = rd.shift;
            int nbuk = (nr + (1 << shift) - 1) >> shift;
            int2* cv_r = cv_base + cvoff;
            int rank_nnz = 0;
            int ncht = 0;
            int chunk0_mat[3] = { 0, 0, 0 };
            for (int i = 0; i < rd.nmats; ++i) {
                chunk0_mat[i] = ncht;
                ncht += (spn[rd.mats[i]] + CHUNK_EDGES - 1) / CHUNK_EDGES;
                rank_nnz += spn[rd.mats[i]];
            }

            for (int i = 0; i < rd.nmats; ++i) {
                int m = rd.mats[i];
                int gch = (spn[m] + CHUNK_EDGES - 1) / CHUNK_EDGES;
                bhist_kernel<<<gch, 256, 0, stream>>>(spr[m], spn[m], shift, nbuk, ncht,
                                                      chunk0_mat[i], HT);
            }
            int nht = nbuk * ncht;
            int nbh = (nht + SCAN_TILE - 1) / SCAN_TILE;
            scan_phase1<<<nbh, 256, 0, stream>>>(HT, bsums, nht);
            scan_phase2<<<1, 256, 0, stream>>>(bsums, nbh);
            scan_phase3<<<nbh, 256, 0, stream>>>(HT, bsums, HS, nht);
            extract_b_kernel<<<(nbuk + 256) / 256, 256, 0, stream>>>(HS, ncht, nbuk,
                                                                     rank_nnz, Bb);

            for (int i = 0; i < rd.nmats; ++i) {
                int m = rd.mats[i];
                int gch = (spn[m] + CHUNK_EDGES - 1) / CHUNK_EDGES;
                bin_kernel<<<gch, 256, 0, stream>>>(spr[m], spc[m], spv[m], spn[m], shift,
                                                    nbuk, ncht, chunk0_mat[i], XB[m], HS, stage);
            }
            binsort_kernel<<<nbuk, 256, 0, stream>>>(stage, Bb, shift, rowptr, cv_r, nr,
                                                     rd.rowbase, (int)cvoff);
            cvoff += (size_t)rank_nnz;
        }
        set_final_kernel<<<1, 1, 0, stream>>>(rowptr + NRC, (int)total_nnz);
    }

    // ---- 4 layers; per-rank gathers ordered right after their producing xw ----
    for (int l = 0; l < 4; ++l) {
        const float* Wl = (l == 0) ? W1 : W234 + (size_t)(l - 1) * 7 * 32 * 32;
        const size_t wst = (l == 0) ? (size_t)64 * 32 : (size_t)32 * 32;
#define WPK(k) (Wl + (size_t)(k) * wst)
#define SLOT(m) (XWbuf + (size_t)XB[m] * 32)
#define G0 gather_kernel<<<(int)(((size_t)N0C * 4 + 255) / 256), 256, 0, stream>>>( \
        rowptr, cv_base, XWbuf, act, AB0, 0.5f, N0C)
#define G1 gather_kernel<<<(int)(((size_t)N1C * 4 + 255) / 256), 256, 0, stream>>>( \
        rowptr, cv_base, XWbuf, act, AB1, 1.f / 3.f, N1C)
#define G2 gather_kernel<<<(int)(((size_t)N2C * 4 + 255) / 256), 256, 0, stream>>>( \
        rowptr, cv_base, XWbuf, act, AB2, 0.5f, N2C)
        if (l == 0) {
            xw_fused_kernel<64, 2, true><<<2048, 256, 0, stream>>>(
                X0, WPK(0), WPK(1), nullptr, SLOT(0), SLOT(4), nullptr, N0C);
            xw_fused_kernel<64, 3, true><<<2048, 256, 0, stream>>>(
                X1, WPK(2), WPK(3), WPK(4), SLOT(1), SLOT(5), SLOT(6), N1C);
            G0;
            xw_fused_kernel<64, 2, true><<<2048, 256, 0, stream>>>(
                X2, WPK(6), WPK(5), nullptr, SLOT(2), SLOT(3), nullptr, N2C);
            G1;
            G2;
        } else if (l < 3) {
            xw_fused_kernel<32, 2, false><<<2048, 256, 0, stream>>>(
                act + (size_t)AB0 * 32, WPK(0), WPK(1), nullptr, SLOT(0), SLOT(4), nullptr, N0C);
            xw_fused_kernel<32, 3, false><<<2048, 256, 0, stream>>>(
                act + (size_t)AB1 * 32, WPK(2), WPK(3), WPK(4), SLOT(1), SLOT(5), SLOT(6), N1C);
            G0;
            xw_fused_kernel<32, 2, false><<<2048, 256, 0, stream>>>(
                act + (size_t)AB2 * 32, WPK(6), WPK(5), nullptr, SLOT(2), SLOT(3), nullptr, N2C);
            G1;
            G2;
        } else {
            // layer 3: only rank-1 output feeds the pool
            xw_fused_kernel<32, 1, false><<<2048, 256, 0, stream>>>(
                act + (size_t)AB0 * 32, WPK(1), nullptr, nullptr, SLOT(4), nullptr, nullptr, N0C);
            xw_fused_kernel<32, 1, false><<<2048, 256, 0, stream>>>(
                act + (size_t)AB1 * 32, WPK(2), nullptr, nullptr, SLOT(1), nullptr, nullptr, N1C);
            xw_fused_kernel<32, 1, false><<<2048, 256, 0, stream>>>(
                act + (size_t)AB2 * 32, WPK(5), nullptr, nullptr, SLOT(3), nullptr, nullptr, N2C);
            G1;
        }
#undef WPK
#undef SLOT
#undef G0
#undef G1
#undef G2
    }

    hipMemsetAsync(sums, 0, (size_t)(NGC * D + NGC) * sizeof(float), stream);
    pool_kernel<<<NGC * BPG, 256, 0, stream>>>(act + (size_t)AB1 * 32, batch1, sums, cnt, N1C);
    head_kernel<<<1, 128, 0, stream>>>(sums, cnt, mlp1_w, mlp1_b, mlp2_w, mlp2_b, out);
}

// Round 12
// 2330.693 us; speedup vs baseline: 1.8681x; 1.0962x over previous
//
#include <hip/hip_runtime.h>
#include <hip/hip_fp16.h>

#define N0C 200000
#define N1C 600000
#define N2C 400000
#define NRC (N0C + N1C + N2C)
#define NGC 128
#define D 32
#define SCAN_TILE 2048
#define CHUNK_EDGES 16384
#define NBUK_MAX 1184
#define LDSE 12288   // max edges per bucket for LDS sort (96 KB)

// act buffer row bases (rank-concatenated)
#define AB0 0
#define AB1 N0C
#define AB2 (N0C + N1C)

typedef __attribute__((ext_vector_type(8))) _Float16 half8;
typedef __attribute__((ext_vector_type(4))) float f32x4;

// ---------- scan helpers (for (bucket,chunk) histogram table) ----------
__global__ void scan_phase1(const int* __restrict__ counts, int* __restrict__ bsums, int n) {
    __shared__ int sd[256];
    int base = blockIdx.x * SCAN_TILE;
    int s = 0;
    for (int i = threadIdx.x; i < SCAN_TILE; i += 256) {
        int idx = base + i;
        s += (idx < n) ? counts[idx] : 0;
    }
    sd[threadIdx.x] = s;
    __syncthreads();
    for (int o = 128; o > 0; o >>= 1) {
        if (threadIdx.x < o) sd[threadIdx.x] += sd[threadIdx.x + o];
        __syncthreads();
    }
    if (threadIdx.x == 0) bsums[blockIdx.x] = sd[0];
}

__global__ void scan_phase2(int* __restrict__ bsums, int nb) {
    __shared__ int sd[1024];
    for (int i = threadIdx.x; i < nb; i += 256) sd[i] = bsums[i];
    __syncthreads();
    if (threadIdx.x == 0) {
        int acc = 0;
        for (int i = 0; i < nb; ++i) { int v = sd[i]; sd[i] = acc; acc += v; }
        bsums[nb] = acc;
    }
    __syncthreads();
    for (int i = threadIdx.x; i < nb; i += 256) bsums[i] = sd[i];
}

__global__ void scan_phase3(const int* __restrict__ counts, const int* __restrict__ bsums,
                            int* __restrict__ outscan, int n) {
    __shared__ int sd[256];
    int base = blockIdx.x * SCAN_TILE + threadIdx.x * 8;
    int v[8];
    int s = 0;
#pragma unroll
    for (int u = 0; u < 8; ++u) {
        int idx = base + u;
        int c = (idx < n) ? counts[idx] : 0;
        v[u] = s;
        s += c;
    }
    sd[threadIdx.x] = s;
    __syncthreads();
    if (threadIdx.x == 0) {
        int acc = bsums[blockIdx.x];
        for (int i = 0; i < 256; ++i) { int q = sd[i]; sd[i] = acc; acc += q; }
    }
    __syncthreads();
    int off = sd[threadIdx.x];
#pragma unroll
    for (int u = 0; u < 8; ++u) {
        int idx = base + u;
        if (idx < n) outscan[idx] = off + v[u];
    }
}

__global__ void set_final_kernel(int* __restrict__ dst, int v) { *dst = v; }

// ---------- binned build phase 1: per-chunk bucket histogram (transposed) ----------
__global__ __launch_bounds__(256) void bhist_kernel(const int* __restrict__ rows, int nnz,
                                                    int shift, int nbuk, int ncht, int chunk0,
                                                    int* __restrict__ HT) {
    __shared__ int h[NBUK_MAX];
    for (int i = threadIdx.x; i < nbuk; i += 256) h[i] = 0;
    __syncthreads();
    int base = blockIdx.x * CHUNK_EDGES;
    for (int i = threadIdx.x; i < CHUNK_EDGES; i += 256) {
        int e = base + i;
        if (e < nnz) atomicAdd(&h[rows[e] >> shift], 1);
    }
    __syncthreads();
    int c = chunk0 + blockIdx.x;
    for (int b = threadIdx.x; b < nbuk; b += 256) HT[b * ncht + c] = h[b];
}

// ---------- binned build phase 2: append into exclusive (bucket,chunk) stage ranges ----------
__global__ __launch_bounds__(256) void bin_kernel(const int* __restrict__ rows,
                                                  const int* __restrict__ cols,
                                                  const float* __restrict__ vals, int nnz,
                                                  int shift, int nbuk, int ncht, int chunk0,
                                                  int colbase, const int* __restrict__ HS,
                                                  int2* __restrict__ stage) {
    __shared__ int cur[NBUK_MAX];
    int c = chunk0 + blockIdx.x;
    for (int b = threadIdx.x; b < nbuk; b += 256) cur[b] = HS[b * ncht + c];
    __syncthreads();
    int base = blockIdx.x * CHUNK_EDGES;
    for (int i = threadIdx.x; i < CHUNK_EDGES; i += 256) {
        int e = base + i;
        if (e < nnz) {
            int r = rows[e];
            int b = r >> shift;
            int pos = atomicAdd(&cur[b], 1);
            int rl = r - (b << shift);
            stage[pos] = make_int2((rl << 22) | (cols[e] + colbase), __float_as_int(vals[e]));
        }
    }
}

__global__ void extract_b_kernel(const int* __restrict__ HS, int ncht, int nbuk, int total,
                                 int* __restrict__ B) {
    int b = blockIdx.x * blockDim.x + threadIdx.x;
    if (b < nbuk) B[b] = HS[b * ncht];
    if (b == nbuk) B[b] = total;
}

// ---------- binned build phase 3: per-bucket LDS counting sort -> GLOBAL rowptr + sequential cv ----------
__global__ __launch_bounds__(256) void binsort_kernel(const int2* __restrict__ stage,
                                                      const int* __restrict__ B, int shift,
                                                      int* __restrict__ rowptr,
                                                      int2* __restrict__ cv, int nrows,
                                                      int rowbase, int cvbase) {
    __shared__ int hcnt[512], sa[512], sb[512], rcur[512];
    __shared__ int2 buf[LDSE];
    int b = blockIdx.x;
    int s0 = B[b], s1 = B[b + 1];
    int cnt = s1 - s0;
    int nr = 1 << shift;
    int rb = b << shift;
    for (int i = threadIdx.x; i < nr; i += 256) hcnt[i] = 0;
    __syncthreads();
    for (int i = s0 + threadIdx.x; i < s1; i += 256)
        atomicAdd(&hcnt[(unsigned)stage[i].x >> 22], 1);
    __syncthreads();
    for (int i = threadIdx.x; i < nr; i += 256) sa[i] = hcnt[i];
    __syncthreads();
    int* curp = sa; int* nxtp = sb;
    for (int off = 1; off < nr; off <<= 1) {
        for (int i = threadIdx.x; i < nr; i += 256)
            nxtp[i] = (i >= off) ? curp[i - off] + curp[i] : curp[i];
        __syncthreads();
        int* t = curp; curp = nxtp; nxtp = t;
    }
    for (int i = threadIdx.x; i < nr; i += 256) {
        int excl = curp[i] - hcnt[i];
        rcur[i] = excl;
        int row = rb + i;
        if (row < nrows) rowptr[rowbase + row] = cvbase + s0 + excl;
    }
    __syncthreads();
    if (cnt <= LDSE) {
        for (int i = s0 + threadIdx.x; i < s1; i += 256) {
            int2 e = stage[i];
            int rl = (unsigned)e.x >> 22;
            int pos = atomicAdd(&rcur[rl], 1);
            buf[pos] = make_int2(e.x & 0x3FFFFF, e.y);
        }
        __syncthreads();
        for (int i = threadIdx.x; i < cnt; i += 256)
            cv[s0 + i] = buf[i];
    } else {
        for (int i = s0 + threadIdx.x; i < s1; i += 256) {
            int2 e = stage[i];
            int rl = (unsigned)e.x >> 22;
            int pos = atomicAdd(&rcur[rl], 1);
            cv[s0 + pos] = make_int2(e.x & 0x3FFFFF, e.y);
        }
    }
}

// ---------- fused MFMA projection (layer 0 only): for NM mats sharing one source ----------
template <int DIN, int NM, bool F32>
__global__ __launch_bounds__(256) void xw_fused_kernel(
    const void* __restrict__ xsrc,
    const float* __restrict__ Wa, const float* __restrict__ Wb, const float* __restrict__ Wc,
    __half* __restrict__ oa, __half* __restrict__ ob, __half* __restrict__ oc, int n) {
    int wave = (blockIdx.x * 256 + threadIdx.x) >> 6;
    int lane = threadIdx.x & 63;
    int nwaves = (gridDim.x * 256) >> 6;
    int li = lane & 15;
    int lk = lane >> 4;
    const float* Ws[3] = { Wa, Wb, Wc };
    __half* Os[3] = { oa, ob, oc };
    half8 bfrag[NM][2][DIN / 32];
#pragma unroll
    for (int m = 0; m < NM; ++m)
#pragma unroll
        for (int ct = 0; ct < 2; ++ct)
#pragma unroll
            for (int ks = 0; ks < DIN / 32; ++ks)
#pragma unroll
                for (int r = 0; r < 8; ++r) {
                    int k = ks * 32 + lk * 8 + r;
                    int j = ct * 16 + li;
                    bfrag[m][ct][ks][r] = (_Float16)Ws[m][k * 32 + j];
                }
    int ntiles = (n + 15) >> 4;
    for (int t = wave; t < ntiles; t += nwaves) {
        int rbase = t << 4;
        int arow = rbase + li;
        int arowc = (arow < n) ? arow : (n - 1);
        half8 afrag[DIN / 32];
#pragma unroll
        for (int ks = 0; ks < DIN / 32; ++ks) {
            if (F32) {
                const float* p = (const float*)xsrc + (size_t)arowc * DIN + ks * 32 + lk * 8;
                float4 u = *(const float4*)p;
                float4 v = *(const float4*)(p + 4);
                afrag[ks] = (half8){ (_Float16)u.x, (_Float16)u.y, (_Float16)u.z, (_Float16)u.w,
                                     (_Float16)v.x, (_Float16)v.y, (_Float16)v.z, (_Float16)v.w };
            } else {
                afrag[ks] = *(const half8*)((const __half*)xsrc + (size_t)arowc * DIN +
                                            ks * 32 + lk * 8);
            }
        }
#pragma unroll
        for (int m = 0; m < NM; ++m) {
#pragma unroll
            for (int ct = 0; ct < 2; ++ct) {
                f32x4 acc = { 0.f, 0.f, 0.f, 0.f };
#pragma unroll
                for (int ks = 0; ks < DIN / 32; ++ks)
                    acc = __builtin_amdgcn_mfma_f32_16x16x32_f16(afrag[ks], bfrag[m][ct][ks],
                                                                 acc, 0, 0, 0);
#pragma unroll
                for (int r = 0; r < 4; ++r) {
                    int row = rbase + lk * 4 + r;
                    if (row < n)
                        Os[m][(size_t)row * 32 + ct * 16 + li] = __float2half(acc[r]);
                }
            }
        }
    }
}

// ---------- layer-0 gather: act-space cols translated to XWbuf slots ----------
// NOTE: no min-waves clause (round-10 lesson: forcing 8 waves/SIMD spills q[8]).
__global__ __launch_bounds__(256) void gather_kernel(
    const int* __restrict__ rp, const int2* __restrict__ cv,
    const __half* __restrict__ XW, __half* __restrict__ act,
    int row0, float scale, int nrange, int t1, int t2, int off0, int off1, int off2) {
    int g = (blockIdx.x * 256 + threadIdx.x) >> 2;
    int j = threadIdx.x & 3;
    if (g >= nrange) return;
    int row = row0 + g;
    int ks = rp[row], ke = rp[row + 1];
    float s[8] = { 0.f, 0.f, 0.f, 0.f, 0.f, 0.f, 0.f, 0.f };
    for (int k = ks; k < ke; k += 8) {
        int2 e[8];
#pragma unroll
        for (int u = 0; u < 8; ++u) {
            int kk = k + u;
            e[u] = cv[(kk < ke) ? kk : (ke - 1)];
        }
        uint4 q[8];
#pragma unroll
        for (int u = 0; u < 8; ++u) {
            int c = e[u].x;
            int add = (c < t1) ? off0 : ((c < t2) ? off1 : off2);
            q[u] = *(const uint4*)(XW + (size_t)(c + add) * 32 + j * 8);
        }
#pragma unroll
        for (int u = 0; u < 8; ++u) {
            float v = (k + u < ke) ? __int_as_float(e[u].y) : 0.f;
            const unsigned* qq = &q[u].x;
#pragma unroll
            for (int h = 0; h < 4; ++h) {
                __half2 h2 = *(__half2*)&qq[h];
                float2 f2 = __half22float2(h2);
                s[2 * h] = fmaf(v, f2.x, s[2 * h]);
                s[2 * h + 1] = fmaf(v, f2.y, s[2 * h + 1]);
            }
        }
    }
    uint4 ov;
    unsigned* op = &ov.x;
#pragma unroll
    for (int h = 0; h < 4; ++h) {
        __half2 o2 = __floats2half2_rn(fmaxf(s[2 * h], 0.f) * scale,
                                       fmaxf(s[2 * h + 1], 0.f) * scale);
        op[h] = *(unsigned*)&o2;
    }
    *(uint4*)(act + (size_t)row * 32 + j * 8) = ov;
}

// ---------- fused gather + W (layers 1..3): S_m = A_m@x per mat, then MFMA W-apply ----------
// Lane map IS the mfma A-frag: row = lane&15, dims = (lane>>4)*8..+8. One wave = 16 rows.
template <int NM>
__global__ __launch_bounds__(256) void gw_kernel(
    const int* __restrict__ rp, const int2* __restrict__ cv,
    const __half* __restrict__ actin, __half* __restrict__ actout,
    const float* __restrict__ Wa, const float* __restrict__ Wb, const float* __restrict__ Wc,
    int t1, int t2, int rowbase, float scale, int ntiles) {
    int gid = (blockIdx.x * 256 + threadIdx.x) >> 6;
    if (gid >= ntiles) return;
    int lane = threadIdx.x & 63;
    int li = lane & 15;
    int lk = lane >> 4;
    int rbase = gid << 4;
    int row = rowbase + rbase + li;
    int ks = rp[row], ke = rp[row + 1];
    float acc[NM][8];
#pragma unroll
    for (int m = 0; m < NM; ++m)
#pragma unroll
        for (int d = 0; d < 8; ++d) acc[m][d] = 0.f;
    for (int k = ks; k < ke; k += 8) {
        int2 e[8];
#pragma unroll
        for (int u = 0; u < 8; ++u) {
            int kk = k + u;
            e[u] = cv[(kk < ke) ? kk : (ke - 1)];
        }
        uint4 q[8];
#pragma unroll
        for (int u = 0; u < 8; ++u)
            q[u] = *(const uint4*)(actin + (size_t)e[u].x * 32 + lk * 8);
#pragma unroll
        for (int u = 0; u < 8; ++u) {
            float bv = (k + u < ke) ? __int_as_float(e[u].y) : 0.f;
            int c = e[u].x;
            float s0, s1, s2;
            if (NM == 2) { s0 = (c < t1) ? bv : 0.f; s1 = bv - s0; s2 = 0.f; }
            else { s0 = (c < t1) ? bv : 0.f; s2 = (c >= t2) ? bv : 0.f; s1 = bv - s0 - s2; }
            const unsigned* qq = &q[u].x;
#pragma unroll
            for (int h = 0; h < 4; ++h) {
                float2 f2 = __half22float2(*(__half2*)&qq[h]);
                acc[0][2 * h] = fmaf(s0, f2.x, acc[0][2 * h]);
                acc[0][2 * h + 1] = fmaf(s0, f2.y, acc[0][2 * h + 1]);
                acc[1][2 * h] = fmaf(s1, f2.x, acc[1][2 * h]);
                acc[1][2 * h + 1] = fmaf(s1, f2.y, acc[1][2 * h + 1]);
                if (NM == 3) {
                    acc[2][2 * h] = fmaf(s2, f2.x, acc[2][2 * h]);
                    acc[2][2 * h + 1] = fmaf(s2, f2.y, acc[2][2 * h + 1]);
                }
            }
        }
    }
    // W-apply: D[16x32] = sum_m A_m[16x32] @ W_m[32x32], two 16-col halves
    const float* Ws[3] = { Wa, Wb, Wc };
    f32x4 d0 = { 0.f, 0.f, 0.f, 0.f };
    f32x4 d1 = { 0.f, 0.f, 0.f, 0.f };
#pragma unroll
    for (int m = 0; m < NM; ++m) {
        half8 a, b0, b1;
#pragma unroll
        for (int r = 0; r < 8; ++r) {
            a[r] = (_Float16)acc[m][r];
            int kk = lk * 8 + r;
            b0[r] = (_Float16)Ws[m][kk * 32 + li];
            b1[r] = (_Float16)Ws[m][kk * 32 + 16 + li];
        }
        d0 = __builtin_amdgcn_mfma_f32_16x16x32_f16(a, b0, d0, 0, 0, 0);
        d1 = __builtin_amdgcn_mfma_f32_16x16x32_f16(a, b1, d1, 0, 0, 0);
    }
    // D frag: col = lane&15, row = (lane>>4)*4 + r
#pragma unroll
    for (int r = 0; r < 4; ++r) {
        size_t orow = (size_t)(rowbase + rbase + lk * 4 + r);
        actout[orow * 32 + li] = __float2half(fmaxf(d0[r], 0.f) * scale);
        actout[orow * 32 + 16 + li] = __float2half(fmaxf(d1[r], 0.f) * scale);
    }
}

// ---------- pooling: per-graph binary search + block reduction ----------
#define BPG 4
__global__ __launch_bounds__(256) void pool_kernel(const __half* __restrict__ x1,
                                                   const int* __restrict__ batch,
                                                   float* __restrict__ sums,
                                                   float* __restrict__ cnt, int n) {
    __shared__ float red[256][8];
    int g = blockIdx.x / BPG;
    int p = blockIdx.x % BPG;
    int lo = 0, hi = n;
    while (lo < hi) { int mid = (lo + hi) >> 1; if (batch[mid] < g) lo = mid + 1; else hi = mid; }
    int s0 = lo;
    lo = s0; hi = n;
    while (lo < hi) { int mid = (lo + hi) >> 1; if (batch[mid] < g + 1) lo = mid + 1; else hi = mid; }
    int s1 = lo;
    int tid = threadIdx.x;
    int qr = tid & 3;
    int rt = tid >> 2;
    float acc[8] = { 0.f, 0.f, 0.f, 0.f, 0.f, 0.f, 0.f, 0.f };
    for (int r = s0 + p * 64 + rt; r < s1; r += BPG * 64) {
        half8 v = *(const half8*)(x1 + (size_t)r * 32 + qr * 8);
#pragma unroll
        for (int u = 0; u < 8; ++u) acc[u] += fabsf((float)v[u]);
    }
#pragma unroll
    for (int u = 0; u < 8; ++u) red[tid][u] = acc[u];
    __syncthreads();
    for (int off = 128; off >= 4; off >>= 1) {
        if (tid < off) {
#pragma unroll
            for (int u = 0; u < 8; ++u) red[tid][u] += red[tid + off][u];
        }
        __syncthreads();
    }
    if (tid < 4) {
#pragma unroll
        for (int u = 0; u < 8; ++u)
            atomicAdd(&sums[(size_t)g * D + tid * 8 + u], red[tid][u]);
    }
    if (p == 0 && tid == 0) cnt[g] = (float)(s1 - s0);
}

// ---------- head ----------
__global__ void head_kernel(const float* __restrict__ sums, const float* __restrict__ cnt,
                            const float* __restrict__ w1, const float* __restrict__ b1,
                            const float* __restrict__ w2, const float* __restrict__ b2,
                            float* __restrict__ out) {
    __shared__ float W1s[D * D], W2s[D * 10], B1s[D], B2s[10];
    int tid = threadIdx.x;
    for (int i = tid; i < D * D; i += blockDim.x) W1s[i] = w1[i];
    for (int i = tid; i < D * 10; i += blockDim.x) W2s[i] = w2[i];
    if (tid < D) B1s[tid] = b1[tid];
    if (tid < 10) B2s[tid] = b2[tid];
    __syncthreads();
    int g = tid;
    if (g >= NGC) return;
    float invc = 1.f / fmaxf(cnt[g], 1.f);
    float p[D];
#pragma unroll
    for (int k = 0; k < D; ++k) p[k] = sums[(size_t)g * D + k] * invc;
    float h[D];
#pragma unroll
    for (int j = 0; j < D; ++j) {
        float s = B1s[j];
#pragma unroll
        for (int k = 0; k < D; ++k) s = fmaf(p[k], W1s[k * D + j], s);
        h[j] = fmaxf(s, 0.f);
    }
    float l[10];
    float m = -1e30f;
#pragma unroll
    for (int o = 0; o < 10; ++o) {
        float s = B2s[o];
#pragma unroll
        for (int k = 0; k < D; ++k) s = fmaf(h[k], W2s[k * 10 + o], s);
        l[o] = s;
        m = fmaxf(m, s);
    }
    float den = 0.f;
#pragma unroll
    for (int o = 0; o < 10; ++o) { l[o] = expf(l[o] - m); den += l[o]; }
    float inv = 1.f / den;
#pragma unroll
    for (int o = 0; o < 10; ++o) out[g * 10 + o] = l[o] * inv;
}

extern "C" void kernel_launch(void* const* d_in, const int* in_sizes, int n_in,
                              void* d_out, int out_size, void* d_ws, size_t ws_size,
                              hipStream_t stream) {
    const float* X0 = (const float*)d_in[0];
    const float* X1 = (const float*)d_in[1];
    const float* X2 = (const float*)d_in[2];
    // mats: 0=L0,1=L1,2=L2,3=B2D3,4=D2B1TD1inv,5=D1invB1,6=B2TD2inv
    const int* spr[7]; const int* spc[7]; const float* spv[7]; int spn[7];
    for (int m = 0; m < 7; ++m) {
        spr[m] = (const int*)d_in[3 + m * 3];
        spc[m] = (const int*)d_in[4 + m * 3];
        spv[m] = (const float*)d_in[5 + m * 3];
        spn[m] = in_sizes[3 + m * 3];
    }
    const int* batch1 = (const int*)d_in[24];
    const float* W1 = (const float*)d_in[25];
    const float* W234 = (const float*)d_in[26];
    const float* mlp1_w = (const float*)d_in[27];
    const float* mlp1_b = (const float*)d_in[28];
    const float* mlp2_w = (const float*)d_in[29];
    const float* mlp2_b = (const float*)d_in[30];
    float* out = (float*)d_out;

    const int srcrows_mat[7] = { N0C, N1C, N2C, N2C, N0C, N1C, N1C };
    // cv columns now in ACT space (source row base)
    const int colbase_mat[7] = { AB0, AB1, AB2, AB2, AB0, AB1, AB1 };
    int XB[7];  // XWbuf slot bases (layer-0 only)
    {
        int acc = 0;
        for (int m = 0; m < 7; ++m) { XB[m] = acc; acc += srcrows_mat[m]; }
    }
    const int XWROWS = 3000000;
    const int IMAX = 0x7fffffff;

    struct RankDef { int nrows; int nmats; int mats[3]; int shift; int rowbase; };
    const RankDef rdefs[3] = {
        { N0C, 2, { 0, 5, -1 }, 8, AB0 },
        { N1C, 3, { 4, 1, 3 }, 9, AB1 },
        { N2C, 2, { 6, 2, -1 }, 9, AB2 },
    };

    // ---- workspace carve ----
    char* wp = (char*)d_ws;
    __half* actA = (__half*)wp;            wp += (size_t)NRC * 32 * sizeof(__half);   // 76.8MB
    __half* XWbuf = (__half*)wp;           wp += (size_t)XWROWS * 32 * sizeof(__half);// 192MB
    __half* actB = XWbuf;                  // aliases XWbuf: XWbuf only live in layer 0
    size_t total_nnz = 0;
    for (int m = 0; m < 7; ++m) total_nnz += (size_t)spn[m];
    int2* cv_base = (int2*)wp;             wp += total_nnz * sizeof(int2);
    int* rowptr = (int*)wp;                wp += (size_t)(NRC + 3) * sizeof(int);
    int* HT = (int*)wp;                    wp += (size_t)1000000 * sizeof(int);
    int* HS = (int*)wp;                    wp += (size_t)1000000 * sizeof(int);
    int* Bb = (int*)wp;                    wp += (size_t)(NBUK_MAX + 1) * sizeof(int);
    int* bsums = (int*)wp;                 wp += 1040 * sizeof(int);
    float* sums = (float*)wp;              wp += (size_t)NGC * D * sizeof(float);
    float* cnt = (float*)wp;               wp += (size_t)NGC * sizeof(float);

    int2* stage = (int2*)XWbuf;  // build completes before layer 0 uses XWbuf

    // ---- build unified CSR (3 rank sections) via binned sort ----
    {
        size_t cvoff = 0;
        for (int r = 0; r < 3; ++r) {
            const RankDef& rd = rdefs[r];
            int nr = rd.nrows;
            int shift = rd.shift;
            int nbuk = (nr + (1 << shift) - 1) >> shift;
            int2* cv_r = cv_base + cvoff;
            int rank_nnz = 0;
            int ncht = 0;
            int chunk0_mat[3] = { 0, 0, 0 };
            for (int i = 0; i < rd.nmats; ++i) {
                chunk0_mat[i] = ncht;
                ncht += (spn[rd.mats[i]] + CHUNK_EDGES - 1) / CHUNK_EDGES;
                rank_nnz += spn[rd.mats[i]];
            }

            for (int i = 0; i < rd.nmats; ++i) {
                int m = rd.mats[i];
                int gch = (spn[m] + CHUNK_EDGES - 1) / CHUNK_EDGES;
                bhist_kernel<<<gch, 256, 0, stream>>>(spr[m], spn[m], shift, nbuk, ncht,
                                                      chunk0_mat[i], HT);
            }
            int nht = nbuk * ncht;
            int nbh = (nht + SCAN_TILE - 1) / SCAN_TILE;
            scan_phase1<<<nbh, 256, 0, stream>>>(HT, bsums, nht);
            scan_phase2<<<1, 256, 0, stream>>>(bsums, nbh);
            scan_phase3<<<nbh, 256, 0, stream>>>(HT, bsums, HS, nht);
            extract_b_kernel<<<(nbuk + 256) / 256, 256, 0, stream>>>(HS, ncht, nbuk,
                                                                     rank_nnz, Bb);

            for (int i = 0; i < rd.nmats; ++i) {
                int m = rd.mats[i];
                int gch = (spn[m] + CHUNK_EDGES - 1) / CHUNK_EDGES;
                bin_kernel<<<gch, 256, 0, stream>>>(spr[m], spc[m], spv[m], spn[m], shift,
                                                    nbuk, ncht, chunk0_mat[i],
                                                    colbase_mat[m], HS, stage);
            }
            binsort_kernel<<<nbuk, 256, 0, stream>>>(stage, Bb, shift, rowptr, cv_r, nr,
                                                     rd.rowbase, (int)cvoff);
            cvoff += (size_t)rank_nnz;
        }
        set_final_kernel<<<1, 1, 0, stream>>>(rowptr + NRC, (int)total_nnz);
    }

#define WPK(Wl, wst, k) ((Wl) + (size_t)(k) * (wst))
#define SLOT(m) (XWbuf + (size_t)XB[m] * 32)

    // ---- layer 0: xw into XWbuf slots, gather with col->slot translation -> actA ----
    {
        const float* Wl = W1;
        const size_t wst = (size_t)64 * 32;
        xw_fused_kernel<64, 2, true><<<2048, 256, 0, stream>>>(
            X0, WPK(Wl, wst, 0), WPK(Wl, wst, 1), nullptr, SLOT(0), SLOT(4), nullptr, N0C);
        xw_fused_kernel<64, 3, true><<<2048, 256, 0, stream>>>(
            X1, WPK(Wl, wst, 2), WPK(Wl, wst, 3), WPK(Wl, wst, 4),
            SLOT(1), SLOT(5), SLOT(6), N1C);
        gather_kernel<<<(int)(((size_t)N0C * 4 + 255) / 256), 256, 0, stream>>>(
            rowptr, cv_base, XWbuf, actA, AB0, 0.5f, N0C,
            AB1, IMAX, XB[0] - AB0, XB[5] - AB1, 0);
        xw_fused_kernel<64, 2, true><<<2048, 256, 0, stream>>>(
            X2, WPK(Wl, wst, 6), WPK(Wl, wst, 5), nullptr, SLOT(2), SLOT(3), nullptr, N2C);
        gather_kernel<<<(int)(((size_t)N1C * 4 + 255) / 256), 256, 0, stream>>>(
            rowptr, cv_base, XWbuf, actA, AB1, 1.f / 3.f, N1C,
            AB1, AB2, XB[4] - AB0, XB[1] - AB1, XB[3] - AB2);
        gather_kernel<<<(int)(((size_t)N2C * 4 + 255) / 256), 256, 0, stream>>>(
            rowptr, cv_base, XWbuf, actA, AB2, 0.5f, N2C,
            AB2, IMAX, XB[6] - AB1, XB[2] - AB2, 0);
    }

    // ---- layers 1..3: fused gather+W (gw), double-buffered act ----
    for (int l = 1; l < 4; ++l) {
        const float* Wl = W234 + (size_t)(l - 1) * 7 * 32 * 32;
        const size_t wst = (size_t)32 * 32;
        const __half* src = (l & 1) ? actA : actB;
        __half* dst = (l & 1) ? actB : actA;
        int nt1 = N1C / 16;
        if (l < 3) {
            int nt0 = N0C / 16, nt2 = N2C / 16;
            gw_kernel<2><<<(nt0 + 3) / 4, 256, 0, stream>>>(
                rowptr, cv_base, src, dst,
                WPK(Wl, wst, 0), WPK(Wl, wst, 3), nullptr,
                AB1, IMAX, AB0, 0.5f, nt0);
            gw_kernel<3><<<(nt1 + 3) / 4, 256, 0, stream>>>(
                rowptr, cv_base, src, dst,
                WPK(Wl, wst, 1), WPK(Wl, wst, 2), WPK(Wl, wst, 5),
                AB1, AB2, AB1, 1.f / 3.f, nt1);
            gw_kernel<2><<<(nt2 + 3) / 4, 256, 0, stream>>>(
                rowptr, cv_base, src, dst,
                WPK(Wl, wst, 4), WPK(Wl, wst, 6), nullptr,
                AB2, IMAX, AB2, 0.5f, nt2);
        } else {
            // layer 3: only rank-1 output feeds the pool
            gw_kernel<3><<<(nt1 + 3) / 4, 256, 0, stream>>>(
                rowptr, cv_base, src, dst,
                WPK(Wl, wst, 1), WPK(Wl, wst, 2), WPK(Wl, wst, 5),
                AB1, AB2, AB1, 1.f / 3.f, nt1);
        }
    }
#undef WPK
#undef SLOT

    hipMemsetAsync(sums, 0, (size_t)(NGC * D + NGC) * sizeof(float), stream);
    pool_kernel<<<NGC * BPG, 256, 0, stream>>>(actB + (size_t)AB1 * 32, batch1, sums, cnt, N1C);
    head_kernel<<<1, 128, 0, stream>>>(sums, cnt, mlp1_w, mlp1_b, mlp2_w, mlp2_b, out);
}

// Round 13
// 2323.549 us; speedup vs baseline: 1.8739x; 1.0031x over previous
//
#include <hip/hip_runtime.h>
#include <hip/hip_fp16.h>

#define N0C 200000
#define N1C 600000
#define N2C 400000
#define NRC (N0C + N1C + N2C)
#define NGC 128
#define D 32
#define SCAN_TILE 2048
#define CHUNK_EDGES 16384
#define NBUK_MAX 2400
#define LDSE 12288
#define BSHIFT 9

#define AB0 0
#define AB1 N0C
#define AB2 (N0C + N1C)
#define IMAXC 0x7fffffff

// XWbuf slot bases (layer-0 projections), compile-time
#define XB0 0
#define XB1 200000
#define XB2 800000
#define XB3 1200000
#define XB4 1600000
#define XB5 1800000
#define XB6 2400000

typedef __attribute__((ext_vector_type(8))) _Float16 half8;
typedef __attribute__((ext_vector_type(4))) float f32x4;

// ---------- scan helpers ----------
__global__ void scan_phase1(const int* __restrict__ counts, int* __restrict__ bsums, int n) {
    __shared__ int sd[256];
    int base = blockIdx.x * SCAN_TILE;
    int s = 0;
    for (int i = threadIdx.x; i < SCAN_TILE; i += 256) {
        int idx = base + i;
        s += (idx < n) ? counts[idx] : 0;
    }
    sd[threadIdx.x] = s;
    __syncthreads();
    for (int o = 128; o > 0; o >>= 1) {
        if (threadIdx.x < o) sd[threadIdx.x] += sd[threadIdx.x + o];
        __syncthreads();
    }
    if (threadIdx.x == 0) bsums[blockIdx.x] = sd[0];
}

__global__ void scan_phase2(int* __restrict__ bsums, int nb) {
    __shared__ int sd[2048];
    for (int i = threadIdx.x; i < nb; i += 256) sd[i] = bsums[i];
    __syncthreads();
    if (threadIdx.x == 0) {
        int acc = 0;
        for (int i = 0; i < nb; ++i) { int v = sd[i]; sd[i] = acc; acc += v; }
        bsums[nb] = acc;
    }
    __syncthreads();
    for (int i = threadIdx.x; i < nb; i += 256) bsums[i] = sd[i];
}

__global__ void scan_phase3(const int* __restrict__ counts, const int* __restrict__ bsums,
                            int* __restrict__ outscan, int n) {
    __shared__ int sd[256];
    int base = blockIdx.x * SCAN_TILE + threadIdx.x * 8;
    int v[8];
    int s = 0;
#pragma unroll
    for (int u = 0; u < 8; ++u) {
        int idx = base + u;
        int c = (idx < n) ? counts[idx] : 0;
        v[u] = s;
        s += c;
    }
    sd[threadIdx.x] = s;
    __syncthreads();
    if (threadIdx.x == 0) {
        int acc = bsums[blockIdx.x];
        for (int i = 0; i < 256; ++i) { int q = sd[i]; sd[i] = acc; acc += q; }
    }
    __syncthreads();
    int off = sd[threadIdx.x];
#pragma unroll
    for (int u = 0; u < 8; ++u) {
        int idx = base + u;
        if (idx < n) outscan[idx] = off + v[u];
    }
}

__global__ void set_final_kernel(int* __restrict__ dst, int v) { *dst = v; }

// ---------- build phase 1: per-chunk global-bucket histogram (transposed) ----------
__global__ __launch_bounds__(256) void bhist_kernel(const int* __restrict__ rows, int nnz,
                                                    int rbase, int nbuk, int ncht, int chunk0,
                                                    int* __restrict__ HT) {
    __shared__ int h[NBUK_MAX];
    for (int i = threadIdx.x; i < nbuk; i += 256) h[i] = 0;
    __syncthreads();
    int base = blockIdx.x * CHUNK_EDGES;
    for (int i = threadIdx.x; i < CHUNK_EDGES; i += 256) {
        int e = base + i;
        if (e < nnz) atomicAdd(&h[(rows[e] + rbase) >> BSHIFT], 1);
    }
    __syncthreads();
    int c = chunk0 + blockIdx.x;
    for (int b = threadIdx.x; b < nbuk; b += 256) HT[b * ncht + c] = h[b];
}

// ---------- build phase 2: append into exclusive (bucket,chunk) stage ranges ----------
__global__ __launch_bounds__(256) void bin_kernel(const int* __restrict__ rows,
                                                  const int* __restrict__ cols,
                                                  const float* __restrict__ vals, int nnz,
                                                  int rbase, int nbuk, int ncht, int chunk0,
                                                  int colbase, const int* __restrict__ HS,
                                                  int2* __restrict__ stage) {
    __shared__ int cur[NBUK_MAX];
    int c = chunk0 + blockIdx.x;
    for (int b = threadIdx.x; b < nbuk; b += 256) cur[b] = HS[b * ncht + c];
    __syncthreads();
    int base = blockIdx.x * CHUNK_EDGES;
    for (int i = threadIdx.x; i < CHUNK_EDGES; i += 256) {
        int e = base + i;
        if (e < nnz) {
            int r = rows[e] + rbase;
            int b = r >> BSHIFT;
            int pos = atomicAdd(&cur[b], 1);
            int rl = r - (b << BSHIFT);
            stage[pos] = make_int2((rl << 22) | (cols[e] + colbase), __float_as_int(vals[e]));
        }
    }
}

__global__ void extract_b_kernel(const int* __restrict__ HS, int ncht, int nbuk, int total,
                                 int* __restrict__ B) {
    int b = blockIdx.x * blockDim.x + threadIdx.x;
    if (b < nbuk) B[b] = HS[b * ncht];
    if (b == nbuk) B[b] = total;
}

// ---------- build phase 3: per-bucket LDS counting sort -> global rowptr + sequential cv ----------
__global__ __launch_bounds__(256) void binsort_kernel(const int2* __restrict__ stage,
                                                      const int* __restrict__ B,
                                                      int* __restrict__ rowptr,
                                                      int2* __restrict__ cv, int nrows) {
    __shared__ int hcnt[512], sa[512], sb[512], rcur[512];
    __shared__ int2 buf[LDSE];
    int b = blockIdx.x;
    int s0 = B[b], s1 = B[b + 1];
    int cnt = s1 - s0;
    int nr = 1 << BSHIFT;
    int rb = b << BSHIFT;
    for (int i = threadIdx.x; i < nr; i += 256) hcnt[i] = 0;
    __syncthreads();
    for (int i = s0 + threadIdx.x; i < s1; i += 256)
        atomicAdd(&hcnt[(unsigned)stage[i].x >> 22], 1);
    __syncthreads();
    for (int i = threadIdx.x; i < nr; i += 256) sa[i] = hcnt[i];
    __syncthreads();
    int* curp = sa; int* nxtp = sb;
    for (int off = 1; off < nr; off <<= 1) {
        for (int i = threadIdx.x; i < nr; i += 256)
            nxtp[i] = (i >= off) ? curp[i - off] + curp[i] : curp[i];
        __syncthreads();
        int* t = curp; curp = nxtp; nxtp = t;
    }
    for (int i = threadIdx.x; i < nr; i += 256) {
        int excl = curp[i] - hcnt[i];
        rcur[i] = excl;
        int row = rb + i;
        if (row < nrows) rowptr[row] = s0 + excl;
    }
    __syncthreads();
    if (cnt <= LDSE) {
        for (int i = s0 + threadIdx.x; i < s1; i += 256) {
            int2 e = stage[i];
            int rl = (unsigned)e.x >> 22;
            int pos = atomicAdd(&rcur[rl], 1);
            buf[pos] = make_int2(e.x & 0x3FFFFF, e.y);
        }
        __syncthreads();
        for (int i = threadIdx.x; i < cnt; i += 256)
            cv[s0 + i] = buf[i];
    } else {
        for (int i = s0 + threadIdx.x; i < s1; i += 256) {
            int2 e = stage[i];
            int rl = (unsigned)e.x >> 22;
            int pos = atomicAdd(&rcur[rl], 1);
            cv[s0 + pos] = make_int2(e.x & 0x3FFFFF, e.y);
        }
    }
}

// ---------- fused MFMA projection (layer 0 only) ----------
template <int DIN, int NM, bool F32>
__global__ __launch_bounds__(256) void xw_fused_kernel(
    const void* __restrict__ xsrc,
    const float* __restrict__ Wa, const float* __restrict__ Wb, const float* __restrict__ Wc,
    __half* __restrict__ oa, __half* __restrict__ ob, __half* __restrict__ oc, int n) {
    int wave = (blockIdx.x * 256 + threadIdx.x) >> 6;
    int lane = threadIdx.x & 63;
    int nwaves = (gridDim.x * 256) >> 6;
    int li = lane & 15;
    int lk = lane >> 4;
    const float* Ws[3] = { Wa, Wb, Wc };
    __half* Os[3] = { oa, ob, oc };
    half8 bfrag[NM][2][DIN / 32];
#pragma unroll
    for (int m = 0; m < NM; ++m)
#pragma unroll
        for (int ct = 0; ct < 2; ++ct)
#pragma unroll
            for (int ks = 0; ks < DIN / 32; ++ks)
#pragma unroll
                for (int r = 0; r < 8; ++r) {
                    int k = ks * 32 + lk * 8 + r;
                    int j = ct * 16 + li;
                    bfrag[m][ct][ks][r] = (_Float16)Ws[m][k * 32 + j];
                }
    int ntiles = (n + 15) >> 4;
    for (int t = wave; t < ntiles; t += nwaves) {
        int rbase = t << 4;
        int arow = rbase + li;
        int arowc = (arow < n) ? arow : (n - 1);
        half8 afrag[DIN / 32];
#pragma unroll
        for (int ks = 0; ks < DIN / 32; ++ks) {
            if (F32) {
                const float* p = (const float*)xsrc + (size_t)arowc * DIN + ks * 32 + lk * 8;
                float4 u = *(const float4*)p;
                float4 v = *(const float4*)(p + 4);
                afrag[ks] = (half8){ (_Float16)u.x, (_Float16)u.y, (_Float16)u.z, (_Float16)u.w,
                                     (_Float16)v.x, (_Float16)v.y, (_Float16)v.z, (_Float16)v.w };
            } else {
                afrag[ks] = *(const half8*)((const __half*)xsrc + (size_t)arowc * DIN +
                                            ks * 32 + lk * 8);
            }
        }
#pragma unroll
        for (int m = 0; m < NM; ++m) {
#pragma unroll
            for (int ct = 0; ct < 2; ++ct) {
                f32x4 acc = { 0.f, 0.f, 0.f, 0.f };
#pragma unroll
                for (int ks = 0; ks < DIN / 32; ++ks)
                    acc = __builtin_amdgcn_mfma_f32_16x16x32_f16(afrag[ks], bfrag[m][ct][ks],
                                                                 acc, 0, 0, 0);
#pragma unroll
                for (int r = 0; r < 4; ++r) {
                    int row = rbase + lk * 4 + r;
                    if (row < n)
                        Os[m][(size_t)row * 32 + ct * 16 + li] = __float2half(acc[r]);
                }
            }
        }
    }
}

// ---------- layer-0 unified gather: all ranks, act-cols -> XWbuf slots ----------
// no min-waves clause (round-10: forcing 8 waves/SIMD spills q[8] -> +2GB scratch traffic)
__global__ __launch_bounds__(256) void gather0_kernel(
    const int* __restrict__ rp, const int2* __restrict__ cv,
    const __half* __restrict__ XW, __half* __restrict__ act, int nrows) {
    int row = (blockIdx.x * 256 + threadIdx.x) >> 2;
    int j = threadIdx.x & 3;
    if (row >= nrows) return;
    int rank = (row >= AB2) ? 2 : ((row >= AB1) ? 1 : 0);
    int t1 = (rank == 2) ? AB2 : AB1;
    int t2 = (rank == 1) ? AB2 : IMAXC;
    int off0 = (rank == 0) ? (XB0 - AB0) : ((rank == 1) ? (XB4 - AB0) : (XB6 - AB1));
    int off1 = (rank == 0) ? (XB5 - AB1) : ((rank == 1) ? (XB1 - AB1) : (XB2 - AB2));
    int off2 = (rank == 1) ? (XB3 - AB2) : 0;
    float scale = (rank == 1) ? (1.f / 3.f) : 0.5f;
    int ks = rp[row], ke = rp[row + 1];
    float s[8] = { 0.f, 0.f, 0.f, 0.f, 0.f, 0.f, 0.f, 0.f };
    for (int k = ks; k < ke; k += 8) {
        int2 e[8];
#pragma unroll
        for (int u = 0; u < 8; ++u) {
            int kk = k + u;
            e[u] = cv[(kk < ke) ? kk : (ke - 1)];
        }
        uint4 q[8];
#pragma unroll
        for (int u = 0; u < 8; ++u) {
            int c = e[u].x;
            int add = (c < t1) ? off0 : ((c < t2) ? off1 : off2);
            q[u] = *(const uint4*)(XW + (size_t)(c + add) * 32 + j * 8);
        }
#pragma unroll
        for (int u = 0; u < 8; ++u) {
            float v = (k + u < ke) ? __int_as_float(e[u].y) : 0.f;
            const unsigned* qq = &q[u].x;
#pragma unroll
            for (int h = 0; h < 4; ++h) {
                float2 f2 = __half22float2(*(__half2*)&qq[h]);
                s[2 * h] = fmaf(v, f2.x, s[2 * h]);
                s[2 * h + 1] = fmaf(v, f2.y, s[2 * h + 1]);
            }
        }
    }
    uint4 ov;
    unsigned* op = &ov.x;
#pragma unroll
    for (int h = 0; h < 4; ++h) {
        __half2 o2 = __floats2half2_rn(fmaxf(s[2 * h], 0.f) * scale,
                                       fmaxf(s[2 * h + 1], 0.f) * scale);
        op[h] = *(unsigned*)&o2;
    }
    *(uint4*)(act + (size_t)row * 32 + j * 8) = ov;
}

// ---------- layers 1..3 unified fused gather+W: rank from tile, NM=3 predicated ----------
__global__ __launch_bounds__(256) void ugw_kernel(
    const int* __restrict__ rp, const int2* __restrict__ cv,
    const __half* __restrict__ actin, __half* __restrict__ actout,
    const float* __restrict__ Wl, int tile0, int ntiles) {
    int gid = (blockIdx.x * 256 + threadIdx.x) >> 6;
    if (gid >= ntiles) return;
    gid += tile0;
    int lane = threadIdx.x & 63;
    int li = lane & 15;
    int lk = lane >> 4;
    int rbase = gid << 4;
    int rank = (rbase >= AB2) ? 2 : ((rbase >= AB1) ? 1 : 0);
    int t1 = (rank == 2) ? AB2 : AB1;
    int t2 = (rank == 1) ? AB2 : IMAXC;
    float scale = (rank == 1) ? (1.f / 3.f) : 0.5f;
    int wk0 = (rank == 0) ? 0 : ((rank == 1) ? 1 : 4);
    int wk1 = (rank == 0) ? 3 : ((rank == 1) ? 2 : 6);
    int wk2 = (rank == 1) ? 5 : 0;  // dummy for rank 0/2 (acc[2]==0)
    const float* Wa = Wl + (size_t)wk0 * 1024;
    const float* Wb = Wl + (size_t)wk1 * 1024;
    const float* Wc = Wl + (size_t)wk2 * 1024;
    int row = rbase + li;
    int ks = rp[row], ke = rp[row + 1];
    float acc[3][8];
#pragma unroll
    for (int m = 0; m < 3; ++m)
#pragma unroll
        for (int d = 0; d < 8; ++d) acc[m][d] = 0.f;
    for (int k = ks; k < ke; k += 8) {
        int2 e[8];
#pragma unroll
        for (int u = 0; u < 8; ++u) {
            int kk = k + u;
            e[u] = cv[(kk < ke) ? kk : (ke - 1)];
        }
        uint4 q[8];
#pragma unroll
        for (int u = 0; u < 8; ++u)
            q[u] = *(const uint4*)(actin + (size_t)e[u].x * 32 + lk * 8);
#pragma unroll
        for (int u = 0; u < 8; ++u) {
            float bv = (k + u < ke) ? __int_as_float(e[u].y) : 0.f;
            int c = e[u].x;
            float s0 = (c < t1) ? bv : 0.f;
            float s2 = (c >= t2) ? bv : 0.f;
            float s1 = bv - s0 - s2;
            const unsigned* qq = &q[u].x;
#pragma unroll
            for (int h = 0; h < 4; ++h) {
                float2 f2 = __half22float2(*(__half2*)&qq[h]);
                acc[0][2 * h] = fmaf(s0, f2.x, acc[0][2 * h]);
                acc[0][2 * h + 1] = fmaf(s0, f2.y, acc[0][2 * h + 1]);
                acc[1][2 * h] = fmaf(s1, f2.x, acc[1][2 * h]);
                acc[1][2 * h + 1] = fmaf(s1, f2.y, acc[1][2 * h + 1]);
                acc[2][2 * h] = fmaf(s2, f2.x, acc[2][2 * h]);
                acc[2][2 * h + 1] = fmaf(s2, f2.y, acc[2][2 * h + 1]);
            }
        }
    }
    const float* Ws[3] = { Wa, Wb, Wc };
    f32x4 d0 = { 0.f, 0.f, 0.f, 0.f };
    f32x4 d1 = { 0.f, 0.f, 0.f, 0.f };
#pragma unroll
    for (int m = 0; m < 3; ++m) {
        half8 a, b0, b1;
#pragma unroll
        for (int r = 0; r < 8; ++r) {
            a[r] = (_Float16)acc[m][r];
            int kk = lk * 8 + r;
            b0[r] = (_Float16)Ws[m][kk * 32 + li];
            b1[r] = (_Float16)Ws[m][kk * 32 + 16 + li];
        }
        d0 = __builtin_amdgcn_mfma_f32_16x16x32_f16(a, b0, d0, 0, 0, 0);
        d1 = __builtin_amdgcn_mfma_f32_16x16x32_f16(a, b1, d1, 0, 0, 0);
    }
#pragma unroll
    for (int r = 0; r < 4; ++r) {
        size_t orow = (size_t)(rbase + lk * 4 + r);
        actout[orow * 32 + li] = __float2half(fmaxf(d0[r], 0.f) * scale);
        actout[orow * 32 + 16 + li] = __float2half(fmaxf(d1[r], 0.f) * scale);
    }
}

// ---------- pooling ----------
#define BPG 4
__global__ __launch_bounds__(256) void pool_kernel(const __half* __restrict__ x1,
                                                   const int* __restrict__ batch,
                                                   float* __restrict__ sums,
                                                   float* __restrict__ cnt, int n) {
    __shared__ float red[256][8];
    int g = blockIdx.x / BPG;
    int p = blockIdx.x % BPG;
    int lo = 0, hi = n;
    while (lo < hi) { int mid = (lo + hi) >> 1; if (batch[mid] < g) lo = mid + 1; else hi = mid; }
    int s0 = lo;
    lo = s0; hi = n;
    while (lo < hi) { int mid = (lo + hi) >> 1; if (batch[mid] < g + 1) lo = mid + 1; else hi = mid; }
    int s1 = lo;
    int tid = threadIdx.x;
    int qr = tid & 3;
    int rt = tid >> 2;
    float acc[8] = { 0.f, 0.f, 0.f, 0.f, 0.f, 0.f, 0.f, 0.f };
    for (int r = s0 + p * 64 + rt; r < s1; r += BPG * 64) {
        half8 v = *(const half8*)(x1 + (size_t)r * 32 + qr * 8);
#pragma unroll
        for (int u = 0; u < 8; ++u) acc[u] += fabsf((float)v[u]);
    }
#pragma unroll
    for (int u = 0; u < 8; ++u) red[tid][u] = acc[u];
    __syncthreads();
    for (int off = 128; off >= 4; off >>= 1) {
        if (tid < off) {
#pragma unroll
            for (int u = 0; u < 8; ++u) red[tid][u] += red[tid + off][u];
        }
        __syncthreads();
    }
    if (tid < 4) {
#pragma unroll
        for (int u = 0; u < 8; ++u)
            atomicAdd(&sums[(size_t)g * D + tid * 8 + u], red[tid][u]);
    }
    if (p == 0 && tid == 0) cnt[g] = (float)(s1 - s0);
}

// ---------- head ----------
__global__ void head_kernel(const float* __restrict__ sums, const float* __restrict__ cnt,
                            const float* __restrict__ w1, const float* __restrict__ b1,
                            const float* __restrict__ w2, const float* __restrict__ b2,
                            float* __restrict__ out) {
    __shared__ float W1s[D * D], W2s[D * 10], B1s[D], B2s[10];
    int tid = threadIdx.x;
    for (int i = tid; i < D * D; i += blockDim.x) W1s[i] = w1[i];
    for (int i = tid; i < D * 10; i += blockDim.x) W2s[i] = w2[i];
    if (tid < D) B1s[tid] = b1[tid];
    if (tid < 10) B2s[tid] = b2[tid];
    __syncthreads();
    int g = tid;
    if (g >= NGC) return;
    float invc = 1.f / fmaxf(cnt[g], 1.f);
    float p[D];
#pragma unroll
    for (int k = 0; k < D; ++k) p[k] = sums[(size_t)g * D + k] * invc;
    float h[D];
#pragma unroll
    for (int j = 0; j < D; ++j) {
        float s = B1s[j];
#pragma unroll
        for (int k = 0; k < D; ++k) s = fmaf(p[k], W1s[k * D + j], s);
        h[j] = fmaxf(s, 0.f);
    }
    float l[10];
    float m = -1e30f;
#pragma unroll
    for (int o = 0; o < 10; ++o) {
        float s = B2s[o];
#pragma unroll
        for (int k = 0; k < D; ++k) s = fmaf(h[k], W2s[k * 10 + o], s);
        l[o] = s;
        m = fmaxf(m, s);
    }
    float den = 0.f;
#pragma unroll
    for (int o = 0; o < 10; ++o) { l[o] = expf(l[o] - m); den += l[o]; }
    float inv = 1.f / den;
#pragma unroll
    for (int o = 0; o < 10; ++o) out[g * 10 + o] = l[o] * inv;
}

extern "C" void kernel_launch(void* const* d_in, const int* in_sizes, int n_in,
                              void* d_out, int out_size, void* d_ws, size_t ws_size,
                              hipStream_t stream) {
    const float* X0 = (const float*)d_in[0];
    const float* X1 = (const float*)d_in[1];
    const float* X2 = (const float*)d_in[2];
    // mats: 0=L0,1=L1,2=L2,3=B2D3,4=D2B1TD1inv,5=D1invB1,6=B2TD2inv
    const int* spr[7]; const int* spc[7]; const float* spv[7]; int spn[7];
    for (int m = 0; m < 7; ++m) {
        spr[m] = (const int*)d_in[3 + m * 3];
        spc[m] = (const int*)d_in[4 + m * 3];
        spv[m] = (const float*)d_in[5 + m * 3];
        spn[m] = in_sizes[3 + m * 3];
    }
    const int* batch1 = (const int*)d_in[24];
    const float* W1 = (const float*)d_in[25];
    const float* W234 = (const float*)d_in[26];
    const float* mlp1_w = (const float*)d_in[27];
    const float* mlp1_b = (const float*)d_in[28];
    const float* mlp2_w = (const float*)d_in[29];
    const float* mlp2_b = (const float*)d_in[30];
    float* out = (float*)d_out;

    // per-mat: output-row base (rank of the mat's rows), source col base (act space)
    const int rowbase_mat[7] = { AB0, AB1, AB2, AB1, AB1, AB0, AB2 };
    const int colbase_mat[7] = { AB0, AB1, AB2, AB2, AB0, AB1, AB1 };
    const int XWROWS = 3000000;

    // ---- workspace carve ----
    char* wp = (char*)d_ws;
    __half* actA = (__half*)wp;            wp += (size_t)NRC * 32 * sizeof(__half);   // 76.8MB
    __half* XWbuf = (__half*)wp;           wp += (size_t)XWROWS * 32 * sizeof(__half);// 192MB
    __half* actB = XWbuf;                  // aliases XWbuf (live only in layer 0)
    size_t total_nnz = 0;
    for (int m = 0; m < 7; ++m) total_nnz += (size_t)spn[m];
    int2* cv_base = (int2*)wp;             wp += total_nnz * sizeof(int2);            // 134.4MB
    int* rowptr = (int*)wp;                wp += (size_t)(NRC + 3) * sizeof(int);
    int* HT = (int*)wp;                    wp += (size_t)3000000 * sizeof(int);
    int* HS = (int*)wp;                    wp += (size_t)3000000 * sizeof(int);
    int* Bb = (int*)wp;                    wp += (size_t)(NBUK_MAX + 1) * sizeof(int);
    int* bsums = (int*)wp;                 wp += 2064 * sizeof(int);
    float* sums = (float*)wp;              wp += (size_t)NGC * D * sizeof(float);
    float* cnt = (float*)wp;               wp += (size_t)NGC * sizeof(float);

    int2* stage = (int2*)XWbuf;  // build completes before layer 0 uses XWbuf

    // ---- unified global-row build: hist -> scan -> bin -> one binsort ----
    {
        int nbuk = (NRC + (1 << BSHIFT) - 1) >> BSHIFT;   // 2344
        int ncht = 0;
        int chunk0_mat[7];
        for (int m = 0; m < 7; ++m) {
            chunk0_mat[m] = ncht;
            ncht += (spn[m] + CHUNK_EDGES - 1) / CHUNK_EDGES;
        }
        for (int m = 0; m < 7; ++m) {
            int gch = (spn[m] + CHUNK_EDGES - 1) / CHUNK_EDGES;
            bhist_kernel<<<gch, 256, 0, stream>>>(spr[m], spn[m], rowbase_mat[m],
                                                  nbuk, ncht, chunk0_mat[m], HT);
        }
        int nht = nbuk * ncht;
        int nbh = (nht + SCAN_TILE - 1) / SCAN_TILE;
        scan_phase1<<<nbh, 256, 0, stream>>>(HT, bsums, nht);
        scan_phase2<<<1, 256, 0, stream>>>(bsums, nbh);
        scan_phase3<<<nbh, 256, 0, stream>>>(HT, bsums, HS, nht);
        extract_b_kernel<<<(nbuk + 257) / 256, 256, 0, stream>>>(HS, ncht, nbuk,
                                                                 (int)total_nnz, Bb);
        for (int m = 0; m < 7; ++m) {
            int gch = (spn[m] + CHUNK_EDGES - 1) / CHUNK_EDGES;
            bin_kernel<<<gch, 256, 0, stream>>>(spr[m], spc[m], spv[m], spn[m],
                                                rowbase_mat[m], nbuk, ncht, chunk0_mat[m],
                                                colbase_mat[m], HS, stage);
        }
        binsort_kernel<<<nbuk, 256, 0, stream>>>(stage, Bb, rowptr, cv_base, NRC);
        set_final_kernel<<<1, 1, 0, stream>>>(rowptr + NRC, (int)total_nnz);
    }

#define WPK(Wl, wst, k) ((Wl) + (size_t)(k) * (wst))

    // ---- layer 0: 3 fused xw into XWbuf slots, one unified gather -> actA ----
    {
        const float* Wl = W1;
        const size_t wst = (size_t)64 * 32;
        xw_fused_kernel<64, 2, true><<<2048, 256, 0, stream>>>(
            X0, WPK(Wl, wst, 0), WPK(Wl, wst, 1), nullptr,
            XWbuf + (size_t)XB0 * 32, XWbuf + (size_t)XB4 * 32, nullptr, N0C);
        xw_fused_kernel<64, 3, true><<<2048, 256, 0, stream>>>(
            X1, WPK(Wl, wst, 2), WPK(Wl, wst, 3), WPK(Wl, wst, 4),
            XWbuf + (size_t)XB1 * 32, XWbuf + (size_t)XB5 * 32,
            XWbuf + (size_t)XB6 * 32, N1C);
        xw_fused_kernel<64, 2, true><<<2048, 256, 0, stream>>>(
            X2, WPK(Wl, wst, 6), WPK(Wl, wst, 5), nullptr,
            XWbuf + (size_t)XB2 * 32, XWbuf + (size_t)XB3 * 32, nullptr, N2C);
        gather0_kernel<<<(int)(((size_t)NRC * 4 + 255) / 256), 256, 0, stream>>>(
            rowptr, cv_base, XWbuf, actA, NRC);
    }

    // ---- layers 1..3: one unified gather+W dispatch each ----
    for (int l = 1; l < 4; ++l) {
        const float* Wl = W234 + (size_t)(l - 1) * 7 * 32 * 32;
        const __half* src = (l & 1) ? actA : actB;
        __half* dst = (l & 1) ? actB : actA;
        if (l < 3) {
            int ntiles = NRC / 16;
            ugw_kernel<<<(ntiles + 3) / 4, 256, 0, stream>>>(
                rowptr, cv_base, src, dst, Wl, 0, ntiles);
        } else {
            int ntiles = N1C / 16;
            ugw_kernel<<<(ntiles + 3) / 4, 256, 0, stream>>>(
                rowptr, cv_base, src, dst, Wl, AB1 / 16, ntiles);
        }
    }
#undef WPK

    hipMemsetAsync(sums, 0, (size_t)(NGC * D + NGC) * sizeof(float), stream);
    pool_kernel<<<NGC * BPG, 256, 0, stream>>>(actB + (size_t)AB1 * 32, batch1, sums, cnt, N1C);
    head_kernel<<<1, 128, 0, stream>>>(sums, cnt, mlp1_w, mlp1_b, mlp2_w, mlp2_b, out);
}

// Round 14
// 2029.515 us; speedup vs baseline: 2.1454x; 1.1449x over previous
//
#include <hip/hip_runtime.h>
#include <hip/hip_fp16.h>

#define N0C 200000
#define N1C 600000
#define N2C 400000
#define NRC (N0C + N1C + N2C)
#define NGC 128
#define D 32
#define CHUNKE 32768
#define BSHIFT 9
#define NBUK ((NRC + 511) >> 9)   // 2344
#define ARENA_S 10224             // arena stride per bucket (edges); mean ~7168, +36 sigma safe
#define LDSE 12288

#define AB0 0
#define AB1 N0C
#define AB2 (N0C + N1C)
#define IMAXC 0x7fffffff

// XWbuf slot bases (layer-0 projections)
#define XB0 0
#define XB1 200000
#define XB2 800000
#define XB3 1200000
#define XB4 1600000
#define XB5 1800000
#define XB6 2400000

typedef __attribute__((ext_vector_type(8))) _Float16 half8;
typedef __attribute__((ext_vector_type(4))) float f32x4;

struct BinArgs {
    const int* rows[7];
    const int* cols[7];
    const float* vals[7];
    int nnz[7];
    int cstart[8];   // cumulative chunk starts
    int rbase[7];    // row base (rank offset) per mat
    int cbase[7];    // col base (act space) per mat
};

// ---------- cursor init: cursor[b] = b * ARENA_S ----------
__global__ void cursor_init_kernel(int* __restrict__ cursor) {
    int b = blockIdx.x * blockDim.x + threadIdx.x;
    if (b < NBUK) cursor[b] = b * ARENA_S;
}

// ---------- fused hist + bin: one pass kernel over all 7 mats ----------
__global__ __launch_bounds__(256) void ubin_kernel(BinArgs A, int* __restrict__ cursor,
                                                   int2* __restrict__ arena) {
    __shared__ int hcnt[NBUK];
    __shared__ int wcur[NBUK];
    int cid = blockIdx.x;
    int m = 0;
    while (cid >= A.cstart[m + 1]) ++m;
    int base = (cid - A.cstart[m]) * CHUNKE;
    const int* rows = A.rows[m];
    const int* cols = A.cols[m];
    const float* vals = A.vals[m];
    int nnz = A.nnz[m];
    int rb = A.rbase[m];
    int cb = A.cbase[m];
    for (int i = threadIdx.x; i < NBUK; i += 256) hcnt[i] = 0;
    __syncthreads();
    for (int i = threadIdx.x; i < CHUNKE; i += 256) {
        int e = base + i;
        if (e < nnz) atomicAdd(&hcnt[(rows[e] + rb) >> BSHIFT], 1);
    }
    __syncthreads();
    for (int b = threadIdx.x; b < NBUK; b += 256) {
        int c = hcnt[b];
        wcur[b] = c ? atomicAdd(&cursor[b], c) : 0;
    }
    __syncthreads();
    for (int i = threadIdx.x; i < CHUNKE; i += 256) {
        int e = base + i;
        if (e < nnz) {
            int r = rows[e] + rb;
            int b = r >> BSHIFT;
            int rl = r & ((1 << BSHIFT) - 1);
            int pos = atomicAdd(&wcur[b], 1);
            arena[pos] = make_int2((rl << 22) | (cols[e] + cb), __float_as_int(vals[e]));
        }
    }
}

// ---------- exclusive scan of bucket counts -> cvbase ----------
__global__ void scan_counts_kernel(const int* __restrict__ cursor, int* __restrict__ cvbase) {
    if (threadIdx.x == 0) {
        int acc = 0;
        for (int b = 0; b < NBUK; ++b) {
            cvbase[b] = acc;
            acc += cursor[b] - b * ARENA_S;
        }
        cvbase[NBUK] = acc;
    }
}

__global__ void set_final_kernel(int* __restrict__ dst, int v) { *dst = v; }

// ---------- per-bucket LDS counting sort: arena -> rowptr + sequential cv ----------
__global__ __launch_bounds__(256) void binsort_kernel(const int2* __restrict__ arena,
                                                      const int* __restrict__ cursor,
                                                      const int* __restrict__ cvbase,
                                                      int* __restrict__ rowptr,
                                                      int2* __restrict__ cv, int nrows) {
    __shared__ int hcnt[512], sa[512], sb[512], rcur[512];
    __shared__ int2 buf[LDSE];
    int b = blockIdx.x;
    int cnt = cursor[b] - b * ARENA_S;
    int cvb = cvbase[b];
    const int2* stage = arena + (size_t)b * ARENA_S;
    int nr = 1 << BSHIFT;
    int rb = b << BSHIFT;
    for (int i = threadIdx.x; i < nr; i += 256) hcnt[i] = 0;
    __syncthreads();
    for (int i = threadIdx.x; i < cnt; i += 256)
        atomicAdd(&hcnt[(unsigned)stage[i].x >> 22], 1);
    __syncthreads();
    for (int i = threadIdx.x; i < nr; i += 256) sa[i] = hcnt[i];
    __syncthreads();
    int* curp = sa; int* nxtp = sb;
    for (int off = 1; off < nr; off <<= 1) {
        for (int i = threadIdx.x; i < nr; i += 256)
            nxtp[i] = (i >= off) ? curp[i - off] + curp[i] : curp[i];
        __syncthreads();
        int* t = curp; curp = nxtp; nxtp = t;
    }
    for (int i = threadIdx.x; i < nr; i += 256) {
        int excl = curp[i] - hcnt[i];
        rcur[i] = excl;
        int row = rb + i;
        if (row < nrows) rowptr[row] = cvb + excl;
    }
    __syncthreads();
    if (cnt <= LDSE) {
        for (int i = threadIdx.x; i < cnt; i += 256) {
            int2 e = stage[i];
            int rl = (unsigned)e.x >> 22;
            int pos = atomicAdd(&rcur[rl], 1);
            buf[pos] = make_int2(e.x & 0x3FFFFF, e.y);
        }
        __syncthreads();
        for (int i = threadIdx.x; i < cnt; i += 256)
            cv[cvb + i] = buf[i];
    } else {
        for (int i = threadIdx.x; i < cnt; i += 256) {
            int2 e = stage[i];
            int rl = (unsigned)e.x >> 22;
            int pos = atomicAdd(&rcur[rl], 1);
            cv[cvb + pos] = make_int2(e.x & 0x3FFFFF, e.y);
        }
    }
}

// ---------- fused MFMA projection (layer 0 only) ----------
template <int DIN, int NM, bool F32>
__global__ __launch_bounds__(256) void xw_fused_kernel(
    const void* __restrict__ xsrc,
    const float* __restrict__ Wa, const float* __restrict__ Wb, const float* __restrict__ Wc,
    __half* __restrict__ oa, __half* __restrict__ ob, __half* __restrict__ oc, int n) {
    int wave = (blockIdx.x * 256 + threadIdx.x) >> 6;
    int lane = threadIdx.x & 63;
    int nwaves = (gridDim.x * 256) >> 6;
    int li = lane & 15;
    int lk = lane >> 4;
    const float* Ws[3] = { Wa, Wb, Wc };
    __half* Os[3] = { oa, ob, oc };
    half8 bfrag[NM][2][DIN / 32];
#pragma unroll
    for (int m = 0; m < NM; ++m)
#pragma unroll
        for (int ct = 0; ct < 2; ++ct)
#pragma unroll
            for (int ks = 0; ks < DIN / 32; ++ks)
#pragma unroll
                for (int r = 0; r < 8; ++r) {
                    int k = ks * 32 + lk * 8 + r;
                    int j = ct * 16 + li;
                    bfrag[m][ct][ks][r] = (_Float16)Ws[m][k * 32 + j];
                }
    int ntiles = (n + 15) >> 4;
    for (int t = wave; t < ntiles; t += nwaves) {
        int rbase = t << 4;
        int arow = rbase + li;
        int arowc = (arow < n) ? arow : (n - 1);
        half8 afrag[DIN / 32];
#pragma unroll
        for (int ks = 0; ks < DIN / 32; ++ks) {
            if (F32) {
                const float* p = (const float*)xsrc + (size_t)arowc * DIN + ks * 32 + lk * 8;
                float4 u = *(const float4*)p;
                float4 v = *(const float4*)(p + 4);
                afrag[ks] = (half8){ (_Float16)u.x, (_Float16)u.y, (_Float16)u.z, (_Float16)u.w,
                                     (_Float16)v.x, (_Float16)v.y, (_Float16)v.z, (_Float16)v.w };
            } else {
                afrag[ks] = *(const half8*)((const __half*)xsrc + (size_t)arowc * DIN +
                                            ks * 32 + lk * 8);
            }
        }
#pragma unroll
        for (int m = 0; m < NM; ++m) {
#pragma unroll
            for (int ct = 0; ct < 2; ++ct) {
                f32x4 acc = { 0.f, 0.f, 0.f, 0.f };
#pragma unroll
                for (int ks = 0; ks < DIN / 32; ++ks)
                    acc = __builtin_amdgcn_mfma_f32_16x16x32_f16(afrag[ks], bfrag[m][ct][ks],
                                                                 acc, 0, 0, 0);
#pragma unroll
                for (int r = 0; r < 4; ++r) {
                    int row = rbase + lk * 4 + r;
                    if (row < n)
                        Os[m][(size_t)row * 32 + ct * 16 + li] = __float2half(acc[r]);
                }
            }
        }
    }
}

// ---------- layer-0 unified gather (act cols -> XWbuf slots) ----------
// no min-waves clause (round-10: forcing 8 waves/SIMD spills q[8] -> scratch traffic)
__global__ __launch_bounds__(256) void gather0_kernel(
    const int* __restrict__ rp, const int2* __restrict__ cv,
    const __half* __restrict__ XW, __half* __restrict__ act, int nrows) {
    int row = (blockIdx.x * 256 + threadIdx.x) >> 2;
    int j = threadIdx.x & 3;
    if (row >= nrows) return;
    int rank = (row >= AB2) ? 2 : ((row >= AB1) ? 1 : 0);
    int t1 = (rank == 2) ? AB2 : AB1;
    int t2 = (rank == 1) ? AB2 : IMAXC;
    int off0 = (rank == 0) ? (XB0 - AB0) : ((rank == 1) ? (XB4 - AB0) : (XB6 - AB1));
    int off1 = (rank == 0) ? (XB5 - AB1) : ((rank == 1) ? (XB1 - AB1) : (XB2 - AB2));
    int off2 = (rank == 1) ? (XB3 - AB2) : 0;
    float scale = (rank == 1) ? (1.f / 3.f) : 0.5f;
    int ks = rp[row], ke = rp[row + 1];
    float s[8] = { 0.f, 0.f, 0.f, 0.f, 0.f, 0.f, 0.f, 0.f };
    for (int k = ks; k < ke; k += 8) {
        int2 e[8];
#pragma unroll
        for (int u = 0; u < 8; ++u) {
            int kk = k + u;
            e[u] = cv[(kk < ke) ? kk : (ke - 1)];
        }
        uint4 q[8];
#pragma unroll
        for (int u = 0; u < 8; ++u) {
            int c = e[u].x;
            int add = (c < t1) ? off0 : ((c < t2) ? off1 : off2);
            q[u] = *(const uint4*)(XW + (size_t)(c + add) * 32 + j * 8);
        }
#pragma unroll
        for (int u = 0; u < 8; ++u) {
            float v = (k + u < ke) ? __int_as_float(e[u].y) : 0.f;
            const unsigned* qq = &q[u].x;
#pragma unroll
            for (int h = 0; h < 4; ++h) {
                float2 f2 = __half22float2(*(__half2*)&qq[h]);
                s[2 * h] = fmaf(v, f2.x, s[2 * h]);
                s[2 * h + 1] = fmaf(v, f2.y, s[2 * h + 1]);
            }
        }
    }
    uint4 ov;
    unsigned* op = &ov.x;
#pragma unroll
    for (int h = 0; h < 4; ++h) {
        __half2 o2 = __floats2half2_rn(fmaxf(s[2 * h], 0.f) * scale,
                                       fmaxf(s[2 * h + 1], 0.f) * scale);
        op[h] = *(unsigned*)&o2;
    }
    *(uint4*)(act + (size_t)row * 32 + j * 8) = ov;
}

// ---------- layers 1..3 unified fused gather+W ----------
__global__ __launch_bounds__(256) void ugw_kernel(
    const int* __restrict__ rp, const int2* __restrict__ cv,
    const __half* __restrict__ actin, __half* __restrict__ actout,
    const float* __restrict__ Wl, int tile0, int ntiles) {
    int gid = (blockIdx.x * 256 + threadIdx.x) >> 6;
    if (gid >= ntiles) return;
    gid += tile0;
    int lane = threadIdx.x & 63;
    int li = lane & 15;
    int lk = lane >> 4;
    int rbase = gid << 4;
    int rank = (rbase >= AB2) ? 2 : ((rbase >= AB1) ? 1 : 0);
    int t1 = (rank == 2) ? AB2 : AB1;
    int t2 = (rank == 1) ? AB2 : IMAXC;
    float scale = (rank == 1) ? (1.f / 3.f) : 0.5f;
    int wk0 = (rank == 0) ? 0 : ((rank == 1) ? 1 : 4);
    int wk1 = (rank == 0) ? 3 : ((rank == 1) ? 2 : 6);
    int wk2 = (rank == 1) ? 5 : 0;
    const float* Wa = Wl + (size_t)wk0 * 1024;
    const float* Wb = Wl + (size_t)wk1 * 1024;
    const float* Wc = Wl + (size_t)wk2 * 1024;
    int row = rbase + li;
    int ks = rp[row], ke = rp[row + 1];
    float acc[3][8];
#pragma unroll
    for (int m = 0; m < 3; ++m)
#pragma unroll
        for (int d = 0; d < 8; ++d) acc[m][d] = 0.f;
    for (int k = ks; k < ke; k += 8) {
        int2 e[8];
#pragma unroll
        for (int u = 0; u < 8; ++u) {
            int kk = k + u;
            e[u] = cv[(kk < ke) ? kk : (ke - 1)];
        }
        uint4 q[8];
#pragma unroll
        for (int u = 0; u < 8; ++u)
            q[u] = *(const uint4*)(actin + (size_t)e[u].x * 32 + lk * 8);
#pragma unroll
        for (int u = 0; u < 8; ++u) {
            float bv = (k + u < ke) ? __int_as_float(e[u].y) : 0.f;
            int c = e[u].x;
            float s0 = (c < t1) ? bv : 0.f;
            float s2 = (c >= t2) ? bv : 0.f;
            float s1 = bv - s0 - s2;
            const unsigned* qq = &q[u].x;
#pragma unroll
            for (int h = 0; h < 4; ++h) {
                float2 f2 = __half22float2(*(__half2*)&qq[h]);
                acc[0][2 * h] = fmaf(s0, f2.x, acc[0][2 * h]);
                acc[0][2 * h + 1] = fmaf(s0, f2.y, acc[0][2 * h + 1]);
                acc[1][2 * h] = fmaf(s1, f2.x, acc[1][2 * h]);
                acc[1][2 * h + 1] = fmaf(s1, f2.y, acc[1][2 * h + 1]);
                acc[2][2 * h] = fmaf(s2, f2.x, acc[2][2 * h]);
                acc[2][2 * h + 1] = fmaf(s2, f2.y, acc[2][2 * h + 1]);
            }
        }
    }
    const float* Ws[3] = { Wa, Wb, Wc };
    f32x4 d0 = { 0.f, 0.f, 0.f, 0.f };
    f32x4 d1 = { 0.f, 0.f, 0.f, 0.f };
#pragma unroll
    for (int m = 0; m < 3; ++m) {
        half8 a, b0, b1;
#pragma unroll
        for (int r = 0; r < 8; ++r) {
            a[r] = (_Float16)acc[m][r];
            int kk = lk * 8 + r;
            b0[r] = (_Float16)Ws[m][kk * 32 + li];
            b1[r] = (_Float16)Ws[m][kk * 32 + 16 + li];
        }
        d0 = __builtin_amdgcn_mfma_f32_16x16x32_f16(a, b0, d0, 0, 0, 0);
        d1 = __builtin_amdgcn_mfma_f32_16x16x32_f16(a, b1, d1, 0, 0, 0);
    }
#pragma unroll
    for (int r = 0; r < 4; ++r) {
        size_t orow = (size_t)(rbase + lk * 4 + r);
        actout[orow * 32 + li] = __float2half(fmaxf(d0[r], 0.f) * scale);
        actout[orow * 32 + 16 + li] = __float2half(fmaxf(d1[r], 0.f) * scale);
    }
}

// ---------- pooling ----------
#define BPG 4
__global__ __launch_bounds__(256) void pool_kernel(const __half* __restrict__ x1,
                                                   const int* __restrict__ batch,
                                                   float* __restrict__ sums,
                                                   float* __restrict__ cnt, int n) {
    __shared__ float red[256][8];
    int g = blockIdx.x / BPG;
    int p = blockIdx.x % BPG;
    int lo = 0, hi = n;
    while (lo < hi) { int mid = (lo + hi) >> 1; if (batch[mid] < g) lo = mid + 1; else hi = mid; }
    int s0 = lo;
    lo = s0; hi = n;
    while (lo < hi) { int mid = (lo + hi) >> 1; if (batch[mid] < g + 1) lo = mid + 1; else hi = mid; }
    int s1 = lo;
    int tid = threadIdx.x;
    int qr = tid & 3;
    int rt = tid >> 2;
    float acc[8] = { 0.f, 0.f, 0.f, 0.f, 0.f, 0.f, 0.f, 0.f };
    for (int r = s0 + p * 64 + rt; r < s1; r += BPG * 64) {
        half8 v = *(const half8*)(x1 + (size_t)r * 32 + qr * 8);
#pragma unroll
        for (int u = 0; u < 8; ++u) acc[u] += fabsf((float)v[u]);
    }
#pragma unroll
    for (int u = 0; u < 8; ++u) red[tid][u] = acc[u];
    __syncthreads();
    for (int off = 128; off >= 4; off >>= 1) {
        if (tid < off) {
#pragma unroll
            for (int u = 0; u < 8; ++u) red[tid][u] += red[tid + off][u];
        }
        __syncthreads();
    }
    if (tid < 4) {
#pragma unroll
        for (int u = 0; u < 8; ++u)
            atomicAdd(&sums[(size_t)g * D + tid * 8 + u], red[tid][u]);
    }
    if (p == 0 && tid == 0) cnt[g] = (float)(s1 - s0);
}

// ---------- head ----------
__global__ void head_kernel(const float* __restrict__ sums, const float* __restrict__ cnt,
                            const float* __restrict__ w1, const float* __restrict__ b1,
                            const float* __restrict__ w2, const float* __restrict__ b2,
                            float* __restrict__ out) {
    __shared__ float W1s[D * D], W2s[D * 10], B1s[D], B2s[10];
    int tid = threadIdx.x;
    for (int i = tid; i < D * D; i += blockDim.x) W1s[i] = w1[i];
    for (int i = tid; i < D * 10; i += blockDim.x) W2s[i] = w2[i];
    if (tid < D) B1s[tid] = b1[tid];
    if (tid < 10) B2s[tid] = b2[tid];
    __syncthreads();
    int g = tid;
    if (g >= NGC) return;
    float invc = 1.f / fmaxf(cnt[g], 1.f);
    float p[D];
#pragma unroll
    for (int k = 0; k < D; ++k) p[k] = sums[(size_t)g * D + k] * invc;
    float h[D];
#pragma unroll
    for (int j = 0; j < D; ++j) {
        float s = B1s[j];
#pragma unroll
        for (int k = 0; k < D; ++k) s = fmaf(p[k], W1s[k * D + j], s);
        h[j] = fmaxf(s, 0.f);
    }
    float l[10];
    float m = -1e30f;
#pragma unroll
    for (int o = 0; o < 10; ++o) {
        float s = B2s[o];
#pragma unroll
        for (int k = 0; k < D; ++k) s = fmaf(h[k], W2s[k * 10 + o], s);
        l[o] = s;
        m = fmaxf(m, s);
    }
    float den = 0.f;
#pragma unroll
    for (int o = 0; o < 10; ++o) { l[o] = expf(l[o] - m); den += l[o]; }
    float inv = 1.f / den;
#pragma unroll
    for (int o = 0; o < 10; ++o) out[g * 10 + o] = l[o] * inv;
}

extern "C" void kernel_launch(void* const* d_in, const int* in_sizes, int n_in,
                              void* d_out, int out_size, void* d_ws, size_t ws_size,
                              hipStream_t stream) {
    const float* X0 = (const float*)d_in[0];
    const float* X1 = (const float*)d_in[1];
    const float* X2 = (const float*)d_in[2];
    // mats: 0=L0,1=L1,2=L2,3=B2D3,4=D2B1TD1inv,5=D1invB1,6=B2TD2inv
    const int* spr[7]; const int* spc[7]; const float* spv[7]; int spn[7];
    for (int m = 0; m < 7; ++m) {
        spr[m] = (const int*)d_in[3 + m * 3];
        spc[m] = (const int*)d_in[4 + m * 3];
        spv[m] = (const float*)d_in[5 + m * 3];
        spn[m] = in_sizes[3 + m * 3];
    }
    const int* batch1 = (const int*)d_in[24];
    const float* W1 = (const float*)d_in[25];
    const float* W234 = (const float*)d_in[26];
    const float* mlp1_w = (const float*)d_in[27];
    const float* mlp1_b = (const float*)d_in[28];
    const float* mlp2_w = (const float*)d_in[29];
    const float* mlp2_b = (const float*)d_in[30];
    float* out = (float*)d_out;

    const int rowbase_mat[7] = { AB0, AB1, AB2, AB1, AB1, AB0, AB2 };
    const int colbase_mat[7] = { AB0, AB1, AB2, AB2, AB0, AB1, AB1 };
    const int XWROWS = 3000000;

    // ---- workspace carve ----
    char* wp = (char*)d_ws;
    __half* actA = (__half*)wp;            wp += (size_t)NRC * 32 * sizeof(__half);   // 76.8MB
    __half* XWbuf = (__half*)wp;           wp += (size_t)XWROWS * 32 * sizeof(__half);// 192MB
    __half* actB = XWbuf;                  // aliases XWbuf (live only in layer 0)
    size_t total_nnz = 0;
    for (int m = 0; m < 7; ++m) total_nnz += (size_t)spn[m];
    int2* cv_base = (int2*)wp;             wp += total_nnz * sizeof(int2);            // 134.4MB
    int* rowptr = (int*)wp;                wp += (size_t)(NRC + 3) * sizeof(int);
    int* cursor = (int*)wp;                wp += (size_t)(NBUK + 4) * sizeof(int);
    int* cvbase = (int*)wp;                wp += (size_t)(NBUK + 4) * sizeof(int);
    float* sums = (float*)wp;              wp += (size_t)NGC * D * sizeof(float);
    float* cnt = (float*)wp;               wp += (size_t)NGC * sizeof(float);

    int2* arena = (int2*)XWbuf;  // 2344*10224*8B = 191.7MB <= 192MB; build ends before layer 0

    // ---- one-pass arena build ----
    {
        BinArgs A;
        int ncht = 0;
        for (int m = 0; m < 7; ++m) {
            A.rows[m] = spr[m];
            A.cols[m] = spc[m];
            A.vals[m] = spv[m];
            A.nnz[m] = spn[m];
            A.rbase[m] = rowbase_mat[m];
            A.cbase[m] = colbase_mat[m];
            A.cstart[m] = ncht;
            ncht += (spn[m] + CHUNKE - 1) / CHUNKE;
        }
        A.cstart[7] = ncht;
        cursor_init_kernel<<<(NBUK + 255) / 256, 256, 0, stream>>>(cursor);
        ubin_kernel<<<ncht, 256, 0, stream>>>(A, cursor, arena);
        scan_counts_kernel<<<1, 64, 0, stream>>>(cursor, cvbase);
        binsort_kernel<<<NBUK, 256, 0, stream>>>(arena, cursor, cvbase, rowptr,
                                                 cv_base, NRC);
        set_final_kernel<<<1, 1, 0, stream>>>(rowptr + NRC, (int)total_nnz);
    }

#define WPK(Wl, wst, k) ((Wl) + (size_t)(k) * (wst))

    // ---- layer 0: 3 fused xw into XWbuf slots, one unified gather -> actA ----
    {
        const float* Wl = W1;
        const size_t wst = (size_t)64 * 32;
        xw_fused_kernel<64, 2, true><<<2048, 256, 0, stream>>>(
            X0, WPK(Wl, wst, 0), WPK(Wl, wst, 1), nullptr,
            XWbuf + (size_t)XB0 * 32, XWbuf + (size_t)XB4 * 32, nullptr, N0C);
        xw_fused_kernel<64, 3, true><<<2048, 256, 0, stream>>>(
            X1, WPK(Wl, wst, 2), WPK(Wl, wst, 3), WPK(Wl, wst, 4),
            XWbuf + (size_t)XB1 * 32, XWbuf + (size_t)XB5 * 32,
            XWbuf + (size_t)XB6 * 32, N1C);
        xw_fused_kernel<64, 2, true><<<2048, 256, 0, stream>>>(
            X2, WPK(Wl, wst, 6), WPK(Wl, wst, 5), nullptr,
            XWbuf + (size_t)XB2 * 32, XWbuf + (size_t)XB3 * 32, nullptr, N2C);
        gather0_kernel<<<(int)(((size_t)NRC * 4 + 255) / 256), 256, 0, stream>>>(
            rowptr, cv_base, XWbuf, actA, NRC);
    }

    // ---- layers 1..3: one unified gather+W dispatch each ----
    for (int l = 1; l < 4; ++l) {
        const float* Wl = W234 + (size_t)(l - 1) * 7 * 32 * 32;
        const __half* src = (l & 1) ? actA : actB;
        __half* dst = (l & 1) ? actB : actA;
        if (l < 3) {
            int ntiles = NRC / 16;
            ugw_kernel<<<(ntiles + 3) / 4, 256, 0, stream>>>(
                rowptr, cv_base, src, dst, Wl, 0, ntiles);
        } else {
            int ntiles = N1C / 16;
            ugw_kernel<<<(ntiles + 3) / 4, 256, 0, stream>>>(
                rowptr, cv_base, src, dst, Wl, AB1 / 16, ntiles);
        }
    }
#undef WPK

    hipMemsetAsync(sums, 0, (size_t)(NGC * D + NGC) * sizeof(float), stream);
    pool_kernel<<<NGC * BPG, 256, 0, stream>>>(actB + (size_t)AB1 * 32, batch1, sums, cnt, N1C);
    head_kernel<<<1, 128, 0, stream>>>(sums, cnt, mlp1_w, mlp1_b, mlp2_w, mlp2_b, out);
}

// Round 15
// 2004.139 us; speedup vs baseline: 2.1725x; 1.0127x over previous
//
#include <hip/hip_runtime.h>
#include <hip/hip_fp16.h>

#define N0C 200000
#define N1C 600000
#define N2C 400000
#define NRC (N0C + N1C + N2C)
#define NGC 128
#define D 32
#define CHUNKE 32768
#define BSHIFT 9
#define NBUK ((NRC + 511) >> 9)   // 2344
#define ARENA_S 11264             // padded bucket stride (edges): real ~7168 + 513*pad(<=7) + margin
#define LDSE 12288

#define AB0 0
#define AB1 N0C
#define AB2 (N0C + N1C)
#define IMAXC 0x7fffffff

// XWbuf slot bases (layer-0 projections)
#define XB0 0
#define XB1 200000
#define XB2 800000
#define XB3 1200000
#define XB4 1600000
#define XB5 1800000
#define XB6 2400000

typedef __attribute__((ext_vector_type(8))) _Float16 half8;
typedef __attribute__((ext_vector_type(4))) float f32x4;

struct BinArgs {
    const int* rows[7];
    const int* cols[7];
    const float* vals[7];
    int nnz[7];
    int cstart[8];
    int rbase[7];
    int cbase[7];
};

// ---------- init: cursor[b] = b*ARENA_S (padded arena positions), realcnt[b] = 0 ----------
__global__ void cursor_init_kernel(int* __restrict__ cursor, int* __restrict__ realcnt) {
    int b = blockIdx.x * blockDim.x + threadIdx.x;
    if (b < NBUK) { cursor[b] = b * ARENA_S; realcnt[b] = 0; }
}

// ---------- fused hist + bin, 64B-exclusive reservations ----------
__global__ __launch_bounds__(256) void ubin_kernel(BinArgs A, int* __restrict__ cursor,
                                                   int* __restrict__ realcnt,
                                                   int2* __restrict__ arena) {
    __shared__ int hcnt[NBUK];
    __shared__ int wcur[NBUK];
    __shared__ int wend[NBUK];
    int cid = blockIdx.x;
    int m = 0;
    while (cid >= A.cstart[m + 1]) ++m;
    int base = (cid - A.cstart[m]) * CHUNKE;
    const int* rows = A.rows[m];
    const int* cols = A.cols[m];
    const float* vals = A.vals[m];
    int nnz = A.nnz[m];
    int rb = A.rbase[m];
    int cb = A.cbase[m];
    for (int i = threadIdx.x; i < NBUK; i += 256) hcnt[i] = 0;
    __syncthreads();
    for (int i = threadIdx.x; i < CHUNKE; i += 256) {
        int e = base + i;
        if (e < nnz) atomicAdd(&hcnt[(rows[e] + rb) >> BSHIFT], 1);
    }
    __syncthreads();
    // reserve 64B-padded exclusive ranges; every arena line has ONE writer block
    for (int b = threadIdx.x; b < NBUK; b += 256) {
        int c = hcnt[b];
        if (c) {
            int pad = (c + 7) & ~7;
            int w = atomicAdd(&cursor[b], pad);
            wcur[b] = w;
            wend[b] = w + pad;
            atomicAdd(&realcnt[b], c);
        } else {
            wcur[b] = 0;
            wend[b] = 0;
        }
    }
    __syncthreads();
    for (int i = threadIdx.x; i < CHUNKE; i += 256) {
        int e = base + i;
        if (e < nnz) {
            int r = rows[e] + rb;
            int b = r >> BSHIFT;
            int rl = r & ((1 << BSHIFT) - 1);
            int pos = atomicAdd(&wcur[b], 1);
            arena[pos] = make_int2((rl << 22) | (cols[e] + cb), __float_as_int(vals[e]));
        }
    }
    __syncthreads();
    // sentinel-fill the pad tail of each reservation (<=7 entries per bucket)
    for (int b = threadIdx.x; b < NBUK; b += 256) {
        for (int i = wcur[b]; i < wend[b]; ++i) arena[i] = make_int2(-1, 0);
    }
}

// ---------- exclusive scan of real bucket counts -> cvbase ----------
__global__ void scan_counts_kernel(const int* __restrict__ realcnt, int* __restrict__ cvbase) {
    if (threadIdx.x == 0) {
        int acc = 0;
        for (int b = 0; b < NBUK; ++b) {
            cvbase[b] = acc;
            acc += realcnt[b];
        }
        cvbase[NBUK] = acc;
    }
}

__global__ void set_final_kernel(int* __restrict__ dst, int v) { *dst = v; }

// ---------- per-bucket LDS counting sort (skips sentinels) ----------
__global__ __launch_bounds__(256) void binsort_kernel(const int2* __restrict__ arena,
                                                      const int* __restrict__ cursor,
                                                      const int* __restrict__ cvbase,
                                                      int* __restrict__ rowptr,
                                                      int2* __restrict__ cv, int nrows) {
    __shared__ int hcnt[512], sa[512], sb[512], rcur[512];
    __shared__ int2 buf[LDSE];
    int b = blockIdx.x;
    int cntp = cursor[b] - b * ARENA_S;   // padded count (includes sentinels)
    int cvb = cvbase[b];
    const int2* stage = arena + (size_t)b * ARENA_S;
    int nr = 1 << BSHIFT;
    int rb = b << BSHIFT;
    for (int i = threadIdx.x; i < nr; i += 256) hcnt[i] = 0;
    __syncthreads();
    for (int i = threadIdx.x; i < cntp; i += 256) {
        unsigned rl = (unsigned)stage[i].x >> 22;
        if (rl < 512u) atomicAdd(&hcnt[rl], 1);
    }
    __syncthreads();
    for (int i = threadIdx.x; i < nr; i += 256) sa[i] = hcnt[i];
    __syncthreads();
    int* curp = sa; int* nxtp = sb;
    for (int off = 1; off < nr; off <<= 1) {
        for (int i = threadIdx.x; i < nr; i += 256)
            nxtp[i] = (i >= off) ? curp[i - off] + curp[i] : curp[i];
        __syncthreads();
        int* t = curp; curp = nxtp; nxtp = t;
    }
    int cntreal = curp[nr - 1];
    for (int i = threadIdx.x; i < nr; i += 256) {
        int excl = curp[i] - hcnt[i];
        rcur[i] = excl;
        int row = rb + i;
        if (row < nrows) rowptr[row] = cvb + excl;
    }
    __syncthreads();
    for (int i = threadIdx.x; i < cntp; i += 256) {
        int2 e = stage[i];
        unsigned rl = (unsigned)e.x >> 22;
        if (rl < 512u) {
            int pos = atomicAdd(&rcur[rl], 1);
            buf[pos] = make_int2(e.x & 0x3FFFFF, e.y);
        }
    }
    __syncthreads();
    for (int i = threadIdx.x; i < cntreal; i += 256)
        cv[cvb + i] = buf[i];
}

// ---------- fused MFMA projection (layer 0 only) ----------
template <int DIN, int NM, bool F32>
__global__ __launch_bounds__(256) void xw_fused_kernel(
    const void* __restrict__ xsrc,
    const float* __restrict__ Wa, const float* __restrict__ Wb, const float* __restrict__ Wc,
    __half* __restrict__ oa, __half* __restrict__ ob, __half* __restrict__ oc, int n) {
    int wave = (blockIdx.x * 256 + threadIdx.x) >> 6;
    int lane = threadIdx.x & 63;
    int nwaves = (gridDim.x * 256) >> 6;
    int li = lane & 15;
    int lk = lane >> 4;
    const float* Ws[3] = { Wa, Wb, Wc };
    __half* Os[3] = { oa, ob, oc };
    half8 bfrag[NM][2][DIN / 32];
#pragma unroll
    for (int m = 0; m < NM; ++m)
#pragma unroll
        for (int ct = 0; ct < 2; ++ct)
#pragma unroll
            for (int ks = 0; ks < DIN / 32; ++ks)
#pragma unroll
                for (int r = 0; r < 8; ++r) {
                    int k = ks * 32 + lk * 8 + r;
                    int j = ct * 16 + li;
                    bfrag[m][ct][ks][r] = (_Float16)Ws[m][k * 32 + j];
                }
    int ntiles = (n + 15) >> 4;
    for (int t = wave; t < ntiles; t += nwaves) {
        int rbase = t << 4;
        int arow = rbase + li;
        int arowc = (arow < n) ? arow : (n - 1);
        half8 afrag[DIN / 32];
#pragma unroll
        for (int ks = 0; ks < DIN / 32; ++ks) {
            if (F32) {
                const float* p = (const float*)xsrc + (size_t)arowc * DIN + ks * 32 + lk * 8;
                float4 u = *(const float4*)p;
                float4 v = *(const float4*)(p + 4);
                afrag[ks] = (half8){ (_Float16)u.x, (_Float16)u.y, (_Float16)u.z, (_Float16)u.w,
                                     (_Float16)v.x, (_Float16)v.y, (_Float16)v.z, (_Float16)v.w };
            } else {
                afrag[ks] = *(const half8*)((const __half*)xsrc + (size_t)arowc * DIN +
                                            ks * 32 + lk * 8);
            }
        }
#pragma unroll
        for (int m = 0; m < NM; ++m) {
#pragma unroll
            for (int ct = 0; ct < 2; ++ct) {
                f32x4 acc = { 0.f, 0.f, 0.f, 0.f };
#pragma unroll
                for (int ks = 0; ks < DIN / 32; ++ks)
                    acc = __builtin_amdgcn_mfma_f32_16x16x32_f16(afrag[ks], bfrag[m][ct][ks],
                                                                 acc, 0, 0, 0);
#pragma unroll
                for (int r = 0; r < 4; ++r) {
                    int row = rbase + lk * 4 + r;
                    if (row < n)
                        Os[m][(size_t)row * 32 + ct * 16 + li] = __float2half(acc[r]);
                }
            }
        }
    }
}

// ---------- layer-0 unified gather (act cols -> XWbuf slots) ----------
// no min-waves clause (round-10: forcing 8 waves/SIMD spills q[8] -> scratch traffic)
__global__ __launch_bounds__(256) void gather0_kernel(
    const int* __restrict__ rp, const int2* __restrict__ cv,
    const __half* __restrict__ XW, __half* __restrict__ act, int nrows) {
    int row = (blockIdx.x * 256 + threadIdx.x) >> 2;
    int j = threadIdx.x & 3;
    if (row >= nrows) return;
    int rank = (row >= AB2) ? 2 : ((row >= AB1) ? 1 : 0);
    int t1 = (rank == 2) ? AB2 : AB1;
    int t2 = (rank == 1) ? AB2 : IMAXC;
    int off0 = (rank == 0) ? (XB0 - AB0) : ((rank == 1) ? (XB4 - AB0) : (XB6 - AB1));
    int off1 = (rank == 0) ? (XB5 - AB1) : ((rank == 1) ? (XB1 - AB1) : (XB2 - AB2));
    int off2 = (rank == 1) ? (XB3 - AB2) : 0;
    float scale = (rank == 1) ? (1.f / 3.f) : 0.5f;
    int ks = rp[row], ke = rp[row + 1];
    float s[8] = { 0.f, 0.f, 0.f, 0.f, 0.f, 0.f, 0.f, 0.f };
    for (int k = ks; k < ke; k += 8) {
        int2 e[8];
#pragma unroll
        for (int u = 0; u < 8; ++u) {
            int kk = k + u;
            e[u] = cv[(kk < ke) ? kk : (ke - 1)];
        }
        uint4 q[8];
#pragma unroll
        for (int u = 0; u < 8; ++u) {
            int c = e[u].x;
            int add = (c < t1) ? off0 : ((c < t2) ? off1 : off2);
            q[u] = *(const uint4*)(XW + (size_t)(c + add) * 32 + j * 8);
        }
#pragma unroll
        for (int u = 0; u < 8; ++u) {
            float v = (k + u < ke) ? __int_as_float(e[u].y) : 0.f;
            const unsigned* qq = &q[u].x;
#pragma unroll
            for (int h = 0; h < 4; ++h) {
                float2 f2 = __half22float2(*(__half2*)&qq[h]);
                s[2 * h] = fmaf(v, f2.x, s[2 * h]);
                s[2 * h + 1] = fmaf(v, f2.y, s[2 * h + 1]);
            }
        }
    }
    uint4 ov;
    unsigned* op = &ov.x;
#pragma unroll
    for (int h = 0; h < 4; ++h) {
        __half2 o2 = __floats2half2_rn(fmaxf(s[2 * h], 0.f) * scale,
                                       fmaxf(s[2 * h + 1], 0.f) * scale);
        op[h] = *(unsigned*)&o2;
    }
    *(uint4*)(act + (size_t)row * 32 + j * 8) = ov;
}

// ---------- layers 1..3 unified fused gather+W ----------
__global__ __launch_bounds__(256) void ugw_kernel(
    const int* __restrict__ rp, const int2* __restrict__ cv,
    const __half* __restrict__ actin, __half* __restrict__ actout,
    const float* __restrict__ Wl, int tile0, int ntiles) {
    int gid = (blockIdx.x * 256 + threadIdx.x) >> 6;
    if (gid >= ntiles) return;
    gid += tile0;
    int lane = threadIdx.x & 63;
    int li = lane & 15;
    int lk = lane >> 4;
    int rbase = gid << 4;
    int rank = (rbase >= AB2) ? 2 : ((rbase >= AB1) ? 1 : 0);
    int t1 = (rank == 2) ? AB2 : AB1;
    int t2 = (rank == 1) ? AB2 : IMAXC;
    float scale = (rank == 1) ? (1.f / 3.f) : 0.5f;
    int wk0 = (rank == 0) ? 0 : ((rank == 1) ? 1 : 4);
    int wk1 = (rank == 0) ? 3 : ((rank == 1) ? 2 : 6);
    int wk2 = (rank == 1) ? 5 : 0;
    const float* Wa = Wl + (size_t)wk0 * 1024;
    const float* Wb = Wl + (size_t)wk1 * 1024;
    const float* Wc = Wl + (size_t)wk2 * 1024;
    int row = rbase + li;
    int ks = rp[row], ke = rp[row + 1];
    float acc[3][8];
#pragma unroll
    for (int m = 0; m < 3; ++m)
#pragma unroll
        for (int d = 0; d < 8; ++d) acc[m][d] = 0.f;
    for (int k = ks; k < ke; k += 8) {
        int2 e[8];
#pragma unroll
        for (int u = 0; u < 8; ++u) {
            int kk = k + u;
            e[u] = cv[(kk < ke) ? kk : (ke - 1)];
        }
        uint4 q[8];
#pragma unroll
        for (int u = 0; u < 8; ++u)
            q[u] = *(const uint4*)(actin + (size_t)e[u].x * 32 + lk * 8);
#pragma unroll
        for (int u = 0; u < 8; ++u) {
            float bv = (k + u < ke) ? __int_as_float(e[u].y) : 0.f;
            int c = e[u].x;
            float s0 = (c < t1) ? bv : 0.f;
            float s2 = (c >= t2) ? bv : 0.f;
            float s1 = bv - s0 - s2;
            const unsigned* qq = &q[u].x;
#pragma unroll
            for (int h = 0; h < 4; ++h) {
                float2 f2 = __half22float2(*(__half2*)&qq[h]);
                acc[0][2 * h] = fmaf(s0, f2.x, acc[0][2 * h]);
                acc[0][2 * h + 1] = fmaf(s0, f2.y, acc[0][2 * h + 1]);
                acc[1][2 * h] = fmaf(s1, f2.x, acc[1][2 * h]);
                acc[1][2 * h + 1] = fmaf(s1, f2.y, acc[1][2 * h + 1]);
                acc[2][2 * h] = fmaf(s2, f2.x, acc[2][2 * h]);
                acc[2][2 * h + 1] = fmaf(s2, f2.y, acc[2][2 * h + 1]);
            }
        }
    }
    const float* Ws[3] = { Wa, Wb, Wc };
    f32x4 d0 = { 0.f, 0.f, 0.f, 0.f };
    f32x4 d1 = { 0.f, 0.f, 0.f, 0.f };
#pragma unroll
    for (int m = 0; m < 3; ++m) {
        half8 a, b0, b1;
#pragma unroll
        for (int r = 0; r < 8; ++r) {
            a[r] = (_Float16)acc[m][r];
            int kk = lk * 8 + r;
            b0[r] = (_Float16)Ws[m][kk * 32 + li];
            b1[r] = (_Float16)Ws[m][kk * 32 + 16 + li];
        }
        d0 = __builtin_amdgcn_mfma_f32_16x16x32_f16(a, b0, d0, 0, 0, 0);
        d1 = __builtin_amdgcn_mfma_f32_16x16x32_f16(a, b1, d1, 0, 0, 0);
    }
#pragma unroll
    for (int r = 0; r < 4; ++r) {
        size_t orow = (size_t)(rbase + lk * 4 + r);
        actout[orow * 32 + li] = __float2half(fmaxf(d0[r], 0.f) * scale);
        actout[orow * 32 + 16 + li] = __float2half(fmaxf(d1[r], 0.f) * scale);
    }
}

// ---------- pooling ----------
#define BPG 4
__global__ __launch_bounds__(256) void pool_kernel(const __half* __restrict__ x1,
                                                   const int* __restrict__ batch,
                                                   float* __restrict__ sums,
                                                   float* __restrict__ cnt, int n) {
    __shared__ float red[256][8];
    int g = blockIdx.x / BPG;
    int p = blockIdx.x % BPG;
    int lo = 0, hi = n;
    while (lo < hi) { int mid = (lo + hi) >> 1; if (batch[mid] < g) lo = mid + 1; else hi = mid; }
    int s0 = lo;
    lo = s0; hi = n;
    while (lo < hi) { int mid = (lo + hi) >> 1; if (batch[mid] < g + 1) lo = mid + 1; else hi = mid; }
    int s1 = lo;
    int tid = threadIdx.x;
    int qr = tid & 3;
    int rt = tid >> 2;
    float acc[8] = { 0.f, 0.f, 0.f, 0.f, 0.f, 0.f, 0.f, 0.f };
    for (int r = s0 + p * 64 + rt; r < s1; r += BPG * 64) {
        half8 v = *(const half8*)(x1 + (size_t)r * 32 + qr * 8);
#pragma unroll
        for (int u = 0; u < 8; ++u) acc[u] += fabsf((float)v[u]);
    }
#pragma unroll
    for (int u = 0; u < 8; ++u) red[tid][u] = acc[u];
    __syncthreads();
    for (int off = 128; off >= 4; off >>= 1) {
        if (tid < off) {
#pragma unroll
            for (int u = 0; u < 8; ++u) red[tid][u] += red[tid + off][u];
        }
        __syncthreads();
    }
    if (tid < 4) {
#pragma unroll
        for (int u = 0; u < 8; ++u)
            atomicAdd(&sums[(size_t)g * D + tid * 8 + u], red[tid][u]);
    }
    if (p == 0 && tid == 0) cnt[g] = (float)(s1 - s0);
}

// ---------- head ----------
__global__ void head_kernel(const float* __restrict__ sums, const float* __restrict__ cnt,
                            const float* __restrict__ w1, const float* __restrict__ b1,
                            const float* __restrict__ w2, const float* __restrict__ b2,
                            float* __restrict__ out) {
    __shared__ float W1s[D * D], W2s[D * 10], B1s[D], B2s[10];
    int tid = threadIdx.x;
    for (int i = tid; i < D * D; i += blockDim.x) W1s[i] = w1[i];
    for (int i = tid; i < D * 10; i += blockDim.x) W2s[i] = w2[i];
    if (tid < D) B1s[tid] = b1[tid];
    if (tid < 10) B2s[tid] = b2[tid];
    __syncthreads();
    int g = tid;
    if (g >= NGC) return;
    float invc = 1.f / fmaxf(cnt[g], 1.f);
    float p[D];
#pragma unroll
    for (int k = 0; k < D; ++k) p[k] = sums[(size_t)g * D + k] * invc;
    float h[D];
#pragma unroll
    for (int j = 0; j < D; ++j) {
        float s = B1s[j];
#pragma unroll
        for (int k = 0; k < D; ++k) s = fmaf(p[k], W1s[k * D + j], s);
        h[j] = fmaxf(s, 0.f);
    }
    float l[10];
    float m = -1e30f;
#pragma unroll
    for (int o = 0; o < 10; ++o) {
        float s = B2s[o];
#pragma unroll
        for (int k = 0; k < D; ++k) s = fmaf(h[k], W2s[k * 10 + o], s);
        l[o] = s;
        m = fmaxf(m, s);
    }
    float den = 0.f;
#pragma unroll
    for (int o = 0; o < 10; ++o) { l[o] = expf(l[o] - m); den += l[o]; }
    float inv = 1.f / den;
#pragma unroll
    for (int o = 0; o < 10; ++o) out[g * 10 + o] = l[o] * inv;
}

extern "C" void kernel_launch(void* const* d_in, const int* in_sizes, int n_in,
                              void* d_out, int out_size, void* d_ws, size_t ws_size,
                              hipStream_t stream) {
    const float* X0 = (const float*)d_in[0];
    const float* X1 = (const float*)d_in[1];
    const float* X2 = (const float*)d_in[2];
    // mats: 0=L0,1=L1,2=L2,3=B2D3,4=D2B1TD1inv,5=D1invB1,6=B2TD2inv
    const int* spr[7]; const int* spc[7]; const float* spv[7]; int spn[7];
    for (int m = 0; m < 7; ++m) {
        spr[m] = (const int*)d_in[3 + m * 3];
        spc[m] = (const int*)d_in[4 + m * 3];
        spv[m] = (const float*)d_in[5 + m * 3];
        spn[m] = in_sizes[3 + m * 3];
    }
    const int* batch1 = (const int*)d_in[24];
    const float* W1 = (const float*)d_in[25];
    const float* W234 = (const float*)d_in[26];
    const float* mlp1_w = (const float*)d_in[27];
    const float* mlp1_b = (const float*)d_in[28];
    const float* mlp2_w = (const float*)d_in[29];
    const float* mlp2_b = (const float*)d_in[30];
    float* out = (float*)d_out;

    const int rowbase_mat[7] = { AB0, AB1, AB2, AB1, AB1, AB0, AB2 };
    const int colbase_mat[7] = { AB0, AB1, AB2, AB2, AB0, AB1, AB1 };
    const int XWROWS = 3000000;

    // ---- workspace carve ----
    char* wp = (char*)d_ws;
    __half* actA = (__half*)wp;            wp += (size_t)NRC * 32 * sizeof(__half);   // 76.8MB
    __half* XWbuf = (__half*)wp;           wp += (size_t)XWROWS * 32 * sizeof(__half);// 192MB
    __half* actB = XWbuf;                  // aliases XWbuf (live only in layer 0)
    size_t total_nnz = 0;
    for (int m = 0; m < 7; ++m) total_nnz += (size_t)spn[m];
    int2* cv_base = (int2*)wp;             wp += total_nnz * sizeof(int2);            // 134.4MB
    int* rowptr = (int*)wp;                wp += (size_t)(NRC + 3) * sizeof(int);
    int* cursor = (int*)wp;                wp += (size_t)(NBUK + 4) * sizeof(int);
    int* realcnt = (int*)wp;               wp += (size_t)(NBUK + 4) * sizeof(int);
    int* cvbase = (int*)wp;                wp += (size_t)(NBUK + 4) * sizeof(int);
    float* sums = (float*)wp;              wp += (size_t)NGC * D * sizeof(float);
    float* cnt = (float*)wp;               wp += (size_t)NGC * sizeof(float);

    // arena aliases [actA .. XWbuf] span: 268.8MB available, need 2344*11264*8 = 211.2MB.
    // Both actA and XWbuf are first written AFTER binsort completes.
    int2* arena = (int2*)actA;

    // ---- one-pass arena build (64B-exclusive reservations) ----
    {
        BinArgs A;
        int ncht = 0;
        for (int m = 0; m < 7; ++m) {
            A.rows[m] = spr[m];
            A.cols[m] = spc[m];
            A.vals[m] = spv[m];
            A.nnz[m] = spn[m];
            A.rbase[m] = rowbase_mat[m];
            A.cbase[m] = colbase_mat[m];
            A.cstart[m] = ncht;
            ncht += (spn[m] + CHUNKE - 1) / CHUNKE;
        }
        A.cstart[7] = ncht;
        cursor_init_kernel<<<(NBUK + 255) / 256, 256, 0, stream>>>(cursor, realcnt);
        ubin_kernel<<<ncht, 256, 0, stream>>>(A, cursor, realcnt, arena);
        scan_counts_kernel<<<1, 64, 0, stream>>>(realcnt, cvbase);
        binsort_kernel<<<NBUK, 256, 0, stream>>>(arena, cursor, cvbase, rowptr,
                                                 cv_base, NRC);
        set_final_kernel<<<1, 1, 0, stream>>>(rowptr + NRC, (int)total_nnz);
    }

#define WPK(Wl, wst, k) ((Wl) + (size_t)(k) * (wst))

    // ---- layer 0: 3 fused xw into XWbuf slots, one unified gather -> actA ----
    {
        const float* Wl = W1;
        const size_t wst = (size_t)64 * 32;
        xw_fused_kernel<64, 2, true><<<2048, 256, 0, stream>>>(
            X0, WPK(Wl, wst, 0), WPK(Wl, wst, 1), nullptr,
            XWbuf + (size_t)XB0 * 32, XWbuf + (size_t)XB4 * 32, nullptr, N0C);
        xw_fused_kernel<64, 3, true><<<2048, 256, 0, stream>>>(
            X1, WPK(Wl, wst, 2), WPK(Wl, wst, 3), WPK(Wl, wst, 4),
            XWbuf + (size_t)XB1 * 32, XWbuf + (size_t)XB5 * 32,
            XWbuf + (size_t)XB6 * 32, N1C);
        xw_fused_kernel<64, 2, true><<<2048, 256, 0, stream>>>(
            X2, WPK(Wl, wst, 6), WPK(Wl, wst, 5), nullptr,
            XWbuf + (size_t)XB2 * 32, XWbuf + (size_t)XB3 * 32, nullptr, N2C);
        gather0_kernel<<<(int)(((size_t)NRC * 4 + 255) / 256), 256, 0, stream>>>(
            rowptr, cv_base, XWbuf, actA, NRC);
    }

    // ---- layers 1..3: one unified gather+W dispatch each ----
    for (int l = 1; l < 4; ++l) {
        const float* Wl = W234 + (size_t)(l - 1) * 7 * 32 * 32;
        const __half* src = (l & 1) ? actA : actB;
        __half* dst = (l & 1) ? actB : actA;
        if (l < 3) {
            int ntiles = NRC / 16;
            ugw_kernel<<<(ntiles + 3) / 4, 256, 0, stream>>>(
                rowptr, cv_base, src, dst, Wl, 0, ntiles);
        } else {
            int ntiles = N1C / 16;
            ugw_kernel<<<(ntiles + 3) / 4, 256, 0, stream>>>(
                rowptr, cv_base, src, dst, Wl, AB1 / 16, ntiles);
        }
    }
#undef WPK

    hipMemsetAsync(sums, 0, (size_t)(NGC * D + NGC) * sizeof(float), stream);
    pool_kernel<<<NGC * BPG, 256, 0, stream>>>(actB + (size_t)AB1 * 32, batch1, sums, cnt, N1C);
    head_kernel<<<1, 128, 0, stream>>>(sums, cnt, mlp1_w, mlp1_b, mlp2_w, mlp2_b, out);
}